// Round 8
// baseline (392.023 us; speedup 1.0000x reference)
//
#include <hip/hip_runtime.h>
#include <math.h>

#define NCAPS 8
#define DD    16
#define D     128
#define M     32
#define ROUTIT 6
#define CUT   5

__device__ __forceinline__ float wred16_sum(float v) {
    v += __shfl_xor(v, 1);
    v += __shfl_xor(v, 2);
    v += __shfl_xor(v, 4);
    v += __shfl_xor(v, 8);
    return v;
}

// ---------------------------------------------------------------- init
__global__ void init_kernel(float* xc0, float* xc1, int n) {
    int t = threadIdx.x;
    if (t < D) {
        xc0[(size_t)n * D + t] = 0.f;   // dummy row n = 0
        xc1[(size_t)n * D + t] = 0.f;
    }
}

// ---------------------------------------------------------------- fused PCA GEMM + attn loss + xc0
// BM=32 rows/block: GEMM holds the full 128-wide h rows in-block, so the
// LayerNorm/QK/softmax/attn-loss and normalize(relu(h)) epilogue runs on the
// LDS-staged tile. h never touches HBM; attn_prep dispatch eliminated.
__global__ __launch_bounds__(256) void pca_attn(
        const float* __restrict__ x, const float* __restrict__ w,
        const float* __restrict__ bias, const float* __restrict__ ln_g,
        const float* __restrict__ ln_b, const float* __restrict__ w_qs,
        const float* __restrict__ w_ks, float* __restrict__ xc0,
        float* __restrict__ partial, int n, int nfeat) {
    __shared__ float xs[20][36];
    __shared__ float ws[20][128];
    __shared__ alignas(16) float hs[32][132];     // h tile, +4 pad
    __shared__ alignas(16) float ks[32][8][20];   // kk vectors, f4-aligned rows
    __shared__ float wq[256], wk[256];
    __shared__ float red[4];
    const int tid = threadIdx.x;
    const int cg = tid & 31;
    const int rg = tid >> 5;
    const int row0 = blockIdx.x * 32;
    wq[tid] = w_qs[tid];
    wk[tid] = w_ks[tid];

    // ---- phase 1: GEMM
    float acc[4][4] = {};
    for (int k0 = 0; k0 < nfeat; k0 += 20) {
#pragma unroll
        for (int i = 0; i < 3; ++i) {
            int l = tid + i * 256;
            if (l < 640) {
                int r = l / 20, kk = l - r * 20;
                int row = row0 + r;
                xs[kk][r] = (row < n) ? x[(size_t)row * nfeat + k0 + kk] : 0.f;
            }
        }
#pragma unroll
        for (int i = 0; i < 10; ++i) {
            int l = tid + i * 256;
            int kk = l >> 7, col = l & 127;
            ws[kk][col] = w[(size_t)(k0 + kk) * 128 + col];
        }
        __syncthreads();
#pragma unroll
        for (int kk = 0; kk < 20; ++kk) {
            float4 a = *(const float4*)&xs[kk][rg * 4];
            float4 b = *(const float4*)&ws[kk][cg * 4];
            float av[4] = {a.x, a.y, a.z, a.w};
            float bv[4] = {b.x, b.y, b.z, b.w};
#pragma unroll
            for (int i = 0; i < 4; ++i)
#pragma unroll
                for (int j = 0; j < 4; ++j) acc[i][j] += av[i] * bv[j];
        }
        __syncthreads();
    }
#pragma unroll
    for (int i = 0; i < 4; ++i)
#pragma unroll
        for (int j = 0; j < 4; ++j)
            hs[rg * 4 + i][cg * 4 + j] = acc[i][j] + bias[cg * 4 + j];
    __syncthreads();

    // ---- phase 2: per-(row, capsule) LN + q/kk matmuls + xc0
    const int r = tid >> 3, kq = tid & 7;
    const int row = row0 + r;
    float hv[16], q[16], kk[16];
    if (row < n) {
#pragma unroll
        for (int i = 0; i < 4; ++i) {
            float4 f = *(const float4*)&hs[r][kq * 16 + i * 4];
            hv[i * 4 + 0] = f.x; hv[i * 4 + 1] = f.y;
            hv[i * 4 + 2] = f.z; hv[i * 4 + 3] = f.w;
        }
        float mu = 0.f;
#pragma unroll
        for (int c = 0; c < 16; ++c) mu += hv[c];
        mu *= (1.f / 16.f);
        float var = 0.f;
#pragma unroll
        for (int c = 0; c < 16; ++c) { float d = hv[c] - mu; var += d * d; }
        var *= (1.f / 16.f);
        float rstd = rsqrtf(var + 1e-6f);
        float qn[16];
#pragma unroll
        for (int c = 0; c < 16; ++c)
            qn[c] = (hv[c] - mu) * rstd * ln_g[c] + ln_b[c];
#pragma unroll
        for (int c = 0; c < 16; ++c) { q[c] = 0.f; kk[c] = 0.f; }
#pragma unroll
        for (int cp = 0; cp < 16; ++cp)
#pragma unroll
            for (int c = 0; c < 16; ++c) {
                q[c]  += qn[cp] * wq[cp * 16 + c];
                kk[c] += hv[cp] * wk[cp * 16 + c];
            }
#pragma unroll
        for (int c = 0; c < 16; ++c) {
            q[c] *= 0.25f;   // 1/sqrt(16)
            ks[r][kq][c] = kk[c];
        }
        // xc0 = normalize(relu(h3)) per capsule — purely local
        float ss = 0.f;
        float rl[16];
#pragma unroll
        for (int c = 0; c < 16; ++c) { rl[c] = fmaxf(hv[c], 0.f); ss += rl[c] * rl[c]; }
        float inv = 1.f / fmaxf(sqrtf(ss), 1e-12f);
        float4* xo = (float4*)(xc0 + (size_t)row * D + kq * DD);
#pragma unroll
        for (int i = 0; i < 4; ++i)
            xo[i] = make_float4(rl[i * 4] * inv, rl[i * 4 + 1] * inv,
                                rl[i * 4 + 2] * inv, rl[i * 4 + 3] * inv);
    }
    __syncthreads();

    // ---- phase 3: scores row kq vs all 8 keys; softmax local; off-diag sum
    float offd = 0.f;
    if (row < n) {
        float s[8];
#pragma unroll
        for (int j = 0; j < 8; ++j) {
            float d = 0.f;
#pragma unroll
            for (int i = 0; i < 4; ++i) {
                float4 f = *(const float4*)&ks[r][j][i * 4];
                d += q[i * 4] * f.x + q[i * 4 + 1] * f.y
                   + q[i * 4 + 2] * f.z + q[i * 4 + 3] * f.w;
            }
            s[j] = d;
        }
        float mx = s[0];
#pragma unroll
        for (int j = 1; j < 8; ++j) mx = fmaxf(mx, s[j]);
        float e[8], se = 0.f;
#pragma unroll
        for (int j = 0; j < 8; ++j) { e[j] = __expf(s[j] - mx); se += e[j]; }
        float rse = 1.f / se;
#pragma unroll
        for (int j = 0; j < 8; ++j)
            if (j != kq) offd += e[j] * rse;
    }
    offd += __shfl_xor(offd, 1);
    offd += __shfl_xor(offd, 2);
    offd += __shfl_xor(offd, 4);
    offd += __shfl_xor(offd, 8);
    offd += __shfl_xor(offd, 16);
    offd += __shfl_xor(offd, 32);
    int lane = tid & 63, wid = tid >> 6;
    if (lane == 0) red[wid] = offd;
    __syncthreads();
    if (tid == 0) partial[blockIdx.x] = red[0] + red[1] + red[2] + red[3];
}

// ---------------------------------------------------------------- partial-sum reduce
__global__ __launch_bounds__(256) void reduce_kernel(
        const float* __restrict__ partial, float* __restrict__ acc, int npart) {
    __shared__ float red[4];
    const int t = threadIdx.x;
    float s = 0.f;
    for (int i = t; i < npart; i += 256) s += partial[i];
    s += __shfl_xor(s, 1);  s += __shfl_xor(s, 2);
    s += __shfl_xor(s, 4);  s += __shfl_xor(s, 8);
    s += __shfl_xor(s, 16); s += __shfl_xor(s, 32);
    if ((t & 63) == 0) red[t >> 6] = s;
    __syncthreads();
    if (t == 0) acc[0] = red[0] + red[1] + red[2] + red[3];
}

// ---------------------------------------------------------------- routing: ONE WAVE PER NODE
// (unchanged from R7 — measured DS-pipe-bound floor ~103 us; see journal)
template <bool LAST>
__global__ __launch_bounds__(64) void routing_kernel(
        const float* __restrict__ xc,   // (n+1)*128, normalized, row n = 0
        const int* __restrict__ nb,     // n*32
        float* __restrict__ out,        // LAST ? u1 : xc_next rows [0,n)
        int* __restrict__ amax, int n) {
    __shared__ alignas(16) float zs[M * D];         // 1024 xor-swizzled float4s
    __shared__ alignas(16) float u_s[NCAPS * 20];   // u[k][c] at k*20+c
    __shared__ alignas(16) float pT[NCAPS * 36];    // pT[k][m]
    const int l = threadIdx.x;
    const int v = blockIdx.x;
    const int m  = l & 31;
    const int kh = l >> 5;
    const int f4 = m;
    const int mg = kh;

    {
        int sm = l >> 1, sh = l & 1;
        int src = 0;
        if (l < M) {
            int nbv = nb[(size_t)v * M + l];
            src = (nbv < 0) ? n : nbv;
        }
        int srow = __shfl(src, sm);
        const float4* g = (const float4*)(xc + (size_t)srow * D);
#pragma unroll
        for (int i = 0; i < 16; ++i) {
            int f = sh * 16 + i;
            ((float4*)zs)[sm * 32 + (f ^ sm)] = g[f];
        }
    }
    float4 x3 = ((const float4*)(xc + (size_t)v * D))[f4];
    __syncthreads();

    {
        float4 a = make_float4(0.f, 0.f, 0.f, 0.f);
#pragma unroll
        for (int j = 0; j < 16; ++j) {
            int r = mg * 16 + j;
            float4 zf = ((const float4*)zs)[r * 32 + (f4 ^ r)];
            a.x += zf.x; a.y += zf.y; a.z += zf.z; a.w += zf.w;
        }
        a.x += __shfl_xor(a.x, 32); a.y += __shfl_xor(a.y, 32);
        a.z += __shfl_xor(a.z, 32); a.w += __shfl_xor(a.w, 32);
        a.x = a.x * 0.125f + x3.x;  a.y = a.y * 0.125f + x3.y;
        a.z = a.z * 0.125f + x3.z;  a.w = a.w * 0.125f + x3.w;
        float ss = a.x * a.x + a.y * a.y + a.z * a.z + a.w * a.w;
        ss += __shfl_xor(ss, 1); ss += __shfl_xor(ss, 2);
        float inv = 1.f / fmaxf(sqrtf(ss), 1e-12f);
        if (l < 32)
            *(float4*)&u_s[(f4 >> 2) * 20 + (f4 & 3) * 4] =
                make_float4(a.x * inv, a.y * inv, a.z * inv, a.w * inv);
    }
    __syncthreads();

    for (int it = 1; it < ROUTIT; ++it) {
        float pr[4];
#pragma unroll
        for (int j = 0; j < 4; ++j) {
            float s = 0.f;
#pragma unroll
            for (int c4 = 0; c4 < 4; ++c4) {
                int f = kh * 16 + j * 4 + c4;
                float4 zf = ((const float4*)zs)[m * 32 + (f ^ m)];
                float4 uf = *(const float4*)&u_s[(kh * 4 + j) * 20 + c4 * 4];
                s += zf.x * uf.x + zf.y * uf.y + zf.z * uf.z + zf.w * uf.w;
            }
            pr[j] = s;
        }
        float po[4];
#pragma unroll
        for (int j = 0; j < 4; ++j) po[j] = __shfl_xor(pr[j], 32);
        if (LAST && it == ROUTIT - 1) {
            float p8[8];
#pragma unroll
            for (int j = 0; j < 4; ++j) {
                p8[kh * 4 + j] = pr[j];
                p8[(kh ^ 1) * 4 + j] = po[j];
            }
            float bv = p8[0]; int bi = 0;
#pragma unroll
            for (int k2 = 1; k2 < 8; ++k2)
                if (p8[k2] > bv) { bv = p8[k2]; bi = k2; }
            if (l < 32) amax[(size_t)v * M + m] = bi;
        }
        float er[4], S = 0.f;
#pragma unroll
        for (int j = 0; j < 4; ++j) { er[j] = __expf(pr[j]); S += er[j]; }
#pragma unroll
        for (int j = 0; j < 4; ++j) S += __expf(po[j]);
        float rS = 1.f / S;
#pragma unroll
        for (int j = 0; j < 4; ++j)
            pT[(kh * 4 + j) * 36 + m] = er[j] * rS;
        __syncthreads();

        float pk[16];
        {
            const int k2 = f4 >> 2;
#pragma unroll
            for (int j4 = 0; j4 < 4; ++j4) {
                float4 pp = *(const float4*)&pT[k2 * 36 + mg * 16 + j4 * 4];
                pk[j4 * 4 + 0] = pp.x; pk[j4 * 4 + 1] = pp.y;
                pk[j4 * 4 + 2] = pp.z; pk[j4 * 4 + 3] = pp.w;
            }
        }
        float4 a = make_float4(0.f, 0.f, 0.f, 0.f);
#pragma unroll
        for (int j = 0; j < 16; ++j) {
            int r = mg * 16 + j;
            float4 zf = ((const float4*)zs)[r * 32 + (f4 ^ r)];
            a.x += zf.x * pk[j]; a.y += zf.y * pk[j];
            a.z += zf.z * pk[j]; a.w += zf.w * pk[j];
        }
        a.x += __shfl_xor(a.x, 32); a.y += __shfl_xor(a.y, 32);
        a.z += __shfl_xor(a.z, 32); a.w += __shfl_xor(a.w, 32);
        a.x += x3.x; a.y += x3.y; a.z += x3.z; a.w += x3.w;

        if (it < ROUTIT - 1) {
            float ss = a.x * a.x + a.y * a.y + a.z * a.z + a.w * a.w;
            ss += __shfl_xor(ss, 1); ss += __shfl_xor(ss, 2);
            float inv = 1.f / fmaxf(sqrtf(ss), 1e-12f);
            if (l < 32)
                *(float4*)&u_s[(f4 >> 2) * 20 + (f4 & 3) * 4] =
                    make_float4(a.x * inv, a.y * inv, a.z * inv, a.w * inv);
            __syncthreads();
        } else if (LAST) {
            if (l < 32) ((float4*)(out + (size_t)v * D))[f4] = a;
        } else {
            float r0 = fmaxf(a.x, 0.f), r1 = fmaxf(a.y, 0.f);
            float r2 = fmaxf(a.z, 0.f), r3 = fmaxf(a.w, 0.f);
            float ss = r0 * r0 + r1 * r1 + r2 * r2 + r3 * r3;
            ss += __shfl_xor(ss, 1); ss += __shfl_xor(ss, 2);
            float inv = 1.f / fmaxf(sqrtf(ss), 1e-12f);
            if (l < 32)
                ((float4*)(out + (size_t)v * D))[f4] =
                    make_float4(r0 * inv, r1 * inv, r2 * inv, r3 * inv);
        }
    }
}

// ---------------------------------------------------------------- second-hop presum
// s2[w][c] = sum_{b<5} xc1[nbm[w,b]][amax[w,b]*16 + c] — depends only on w;
// previously recomputed ~5x per consuming node inside meta (25 gathers -> 5+5).
__global__ __launch_bounds__(256) void s2_kernel(
        const float* __restrict__ xc1, const int* __restrict__ nb,
        const int* __restrict__ amax, float* __restrict__ s2, int n) {
    int idx = blockIdx.x * 256 + threadIdx.x;
    if (idx >= n * 16) return;
    int w = idx >> 4, c = idx & 15;
    float s = 0.f;
#pragma unroll
    for (int b = 0; b < CUT; ++b) {
        int t  = nb[(size_t)w * M + b];
        int jj = amax[(size_t)w * M + b];
        int im = (t < 0) ? n : t;   // row n = zeros
        s += xc1[(size_t)im * D + jj * DD + c];
    }
    s2[idx] = s;
}

// ---------------------------------------------------------------- meta gather + MLP + log_softmax
__global__ __launch_bounds__(256) void meta_kernel(
        const float* __restrict__ u1, const float* __restrict__ s2,
        const int* __restrict__ nb, const int* __restrict__ amax,
        const float* __restrict__ mlp_w, const float* __restrict__ mlp_b,
        const float* __restrict__ attn_acc, float* __restrict__ d_out, int n) {
    __shared__ float Wl[128 * 16];
    __shared__ float accs[16][132];
    const int t = threadIdx.x;
#pragma unroll
    for (int i = 0; i < 8; ++i) Wl[t + i * 256] = mlp_w[t + i * 256];
    const int g = t >> 4, c = t & 15;
    const int v = blockIdx.x * 16 + g;
    if (blockIdx.x == 0 && t == 0)
        d_out[(size_t)n * 16] = attn_acc[0] * (1.f / (56.f * (float)n));
    if (v < n) {
#pragma unroll
        for (int i = 0; i < 8; ++i) accs[g][i * 16 + c] = 0.f;
        for (int a = 0; a < CUT; ++a) {
            int w = nb[(size_t)v * M + a];
            if (w < 0) continue;
            int i = amax[(size_t)v * M + a];   // first-hop capsule
            accs[g][i * 16 + c] += s2[(size_t)w * 16 + c];
        }
#pragma unroll
        for (int i = 0; i < 8; ++i) {
            float meta = u1[(size_t)v * D + i * 16 + c] + accs[g][i * 16 + c] * (1.f / 25.f);
            accs[g][i * 16 + c] = fmaxf(meta, 0.f);
        }
    }
    __syncthreads();
    if (v < n) {
        float o = mlp_b[c];
#pragma unroll
        for (int dd = 0; dd < 128; ++dd) o += accs[g][dd] * Wl[dd * 16 + c];
        float mx = o;
        mx = fmaxf(mx, __shfl_xor(mx, 1));
        mx = fmaxf(mx, __shfl_xor(mx, 2));
        mx = fmaxf(mx, __shfl_xor(mx, 4));
        mx = fmaxf(mx, __shfl_xor(mx, 8));
        float e = __expf(o - mx);
        float se = wred16_sum(e);
        float ls = (o - mx) - logf(se);
        d_out[(size_t)v * 16 + c] = ls;
        d_out[(size_t)n * 16 + 1 + (size_t)v * 16 + c] = o;
    }
}

// ---------------------------------------------------------------- launch
extern "C" void kernel_launch(void* const* d_in, const int* in_sizes, int n_in,
                              void* d_out, int out_size, void* d_ws, size_t ws_size,
                              hipStream_t stream) {
    const float* x     = (const float*)d_in[0];
    const int*   nb    = (const int*)d_in[1];
    const float* pca_w = (const float*)d_in[2];
    const float* pca_b = (const float*)d_in[3];
    const float* ln_g  = (const float*)d_in[4];
    const float* ln_b  = (const float*)d_in[5];
    const float* w_qs  = (const float*)d_in[6];
    const float* w_ks  = (const float*)d_in[7];
    const float* mlp_w = (const float*)d_in[8];
    const float* mlp_b = (const float*)d_in[9];
    float* out = (float*)d_out;

    const int d = 128;
    const int nfeat = in_sizes[2] / d;      // 500
    const int n = in_sizes[0] / nfeat;      // 20000
    const int nblk = (n + 31) / 32;         // fused pca_attn blocks (625)

    float* bufA = (float*)d_ws;                       // n*128 : u1
    float* bufB = bufA + (size_t)n * d;               // (n+1)*128 : xc0; later amax+s2
    float* bufC = bufB + (size_t)(n + 1) * d;         // (n+1)*128 : xc1
    float* acc  = bufC + (size_t)(n + 1) * d;         // 1 float : attn loss sum
    int* amax = (int*)bufB;                           // n*32 ints (xc0 dead)
    float* s2 = bufB + (size_t)n * M;                 // n*16 floats, after amax
    // attn partials overlay the head of bufC: consumed by reduce_kernel
    // before routing<false> writes bufC; row n untouched.
    float* partial = bufC;

    init_kernel<<<1, 256, 0, stream>>>(bufB, bufC, n);
    pca_attn<<<nblk, 256, 0, stream>>>(x, pca_w, pca_b, ln_g, ln_b, w_qs, w_ks,
                                       bufB, partial, n, nfeat);
    reduce_kernel<<<1, 256, 0, stream>>>(partial, acc, nblk);
    routing_kernel<false><<<n, 64, 0, stream>>>(bufB, nb, bufC, nullptr, n);
    routing_kernel<true><<<n, 64, 0, stream>>>(bufC, nb, bufA, amax, n);
    s2_kernel<<<(n * 16 + 255) / 256, 256, 0, stream>>>(bufC, nb, amax, s2, n);
    meta_kernel<<<(n + 15) / 16, 256, 0, stream>>>(bufA, s2, nb, amax, mlp_w, mlp_b, acc, out, n);
}

// Round 9
// 341.989 us; speedup vs baseline: 1.1463x; 1.1463x over previous
//
#include <hip/hip_runtime.h>
#include <math.h>

#define NCAPS 8
#define DD    16
#define D     128
#define M     32
#define ROUTIT 6
#define CUT   5

__device__ __forceinline__ float wred16_sum(float v) {
    v += __shfl_xor(v, 1);
    v += __shfl_xor(v, 2);
    v += __shfl_xor(v, 4);
    v += __shfl_xor(v, 8);
    return v;
}

// ---------------------------------------------------------------- init
__global__ void init_kernel(float* xc0, float* xc1, int n) {
    int t = threadIdx.x;
    if (t < D) {
        xc0[(size_t)n * D + t] = 0.f;   // dummy row n = 0
        xc1[(size_t)n * D + t] = 0.f;
    }
}

// ---------------------------------------------------------------- fused PCA GEMM + attn loss + xc0
// R9: fully vectorized staging. R8's 136us was latency starvation from
// 640 scattered 4B x-loads/tile (stride-2000B) + 2560 scalar w-loads/tile
// with only ~2.4 blocks/CU to hide them. Now: x tile = 160 coalesced f4
// (4x fewer lines), w tile = 640 f4, hs/ks stores b128.
__global__ __launch_bounds__(256) void pca_attn(
        const float* __restrict__ x, const float* __restrict__ w,
        const float* __restrict__ bias, const float* __restrict__ ln_g,
        const float* __restrict__ ln_b, const float* __restrict__ w_qs,
        const float* __restrict__ w_ks, float* __restrict__ xc0,
        float* __restrict__ partial, int n, int nfeat) {
    __shared__ float xs[20][36];                  // [kk][r]
    __shared__ alignas(16) float ws[20][128];     // [kk][col]
    __shared__ alignas(16) float hs[32][132];     // h tile, +4 pad
    __shared__ alignas(16) float ks[32][8][20];   // kk vectors, f4-aligned rows
    __shared__ float wq[256], wk[256];
    __shared__ float red[4];
    const int tid = threadIdx.x;
    const int cg = tid & 31;
    const int rg = tid >> 5;
    const int row0 = blockIdx.x * 32;
    wq[tid] = w_qs[tid];
    wk[tid] = w_ks[tid];
    const float4 bi4 = *(const float4*)&bias[cg * 4];

    // ---- phase 1: GEMM (BM=32, BN=128, BK=20, 4x4 microtile)
    float acc[4][4] = {};
    for (int k0 = 0; k0 < nfeat; k0 += 20) {
        // x tile: 32 rows x 20 cols = 160 float4, coalesced
        if (tid < 160) {
            int r = tid / 5, cf = tid % 5;
            int row = row0 + r;
            float4 f = (row < n)
                ? *(const float4*)&x[(size_t)row * nfeat + k0 + cf * 4]
                : make_float4(0.f, 0.f, 0.f, 0.f);
            xs[cf * 4 + 0][r] = f.x; xs[cf * 4 + 1][r] = f.y;
            xs[cf * 4 + 2][r] = f.z; xs[cf * 4 + 3][r] = f.w;
        }
        // w tile: 20 x 128 = 640 float4, coalesced
#pragma unroll
        for (int i = 0; i < 3; ++i) {
            int f = tid + i * 256;
            if (f < 640) {
                int kk = f >> 5, c4 = f & 31;
                *(float4*)&ws[kk][c4 * 4] =
                    *(const float4*)&w[(size_t)(k0 + kk) * 128 + c4 * 4];
            }
        }
        __syncthreads();
#pragma unroll
        for (int kk = 0; kk < 20; ++kk) {
            float4 a = *(const float4*)&xs[kk][rg * 4];
            float4 b = *(const float4*)&ws[kk][cg * 4];
            float av[4] = {a.x, a.y, a.z, a.w};
            float bv[4] = {b.x, b.y, b.z, b.w};
#pragma unroll
            for (int i = 0; i < 4; ++i)
#pragma unroll
                for (int j = 0; j < 4; ++j) acc[i][j] += av[i] * bv[j];
        }
        __syncthreads();
    }
#pragma unroll
    for (int i = 0; i < 4; ++i)
        *(float4*)&hs[rg * 4 + i][cg * 4] =
            make_float4(acc[i][0] + bi4.x, acc[i][1] + bi4.y,
                        acc[i][2] + bi4.z, acc[i][3] + bi4.w);
    __syncthreads();

    // ---- phase 2: per-(row, capsule) LN + q/kk matmuls + xc0
    const int r = tid >> 3, kq = tid & 7;
    const int row = row0 + r;
    float hv[16], q[16], kk[16];
    if (row < n) {
#pragma unroll
        for (int i = 0; i < 4; ++i) {
            float4 f = *(const float4*)&hs[r][kq * 16 + i * 4];
            hv[i * 4 + 0] = f.x; hv[i * 4 + 1] = f.y;
            hv[i * 4 + 2] = f.z; hv[i * 4 + 3] = f.w;
        }
        float mu = 0.f;
#pragma unroll
        for (int c = 0; c < 16; ++c) mu += hv[c];
        mu *= (1.f / 16.f);
        float var = 0.f;
#pragma unroll
        for (int c = 0; c < 16; ++c) { float d = hv[c] - mu; var += d * d; }
        var *= (1.f / 16.f);
        float rstd = rsqrtf(var + 1e-6f);
        float qn[16];
#pragma unroll
        for (int c = 0; c < 16; ++c)
            qn[c] = (hv[c] - mu) * rstd * ln_g[c] + ln_b[c];
#pragma unroll
        for (int c = 0; c < 16; ++c) { q[c] = 0.f; kk[c] = 0.f; }
#pragma unroll
        for (int cp = 0; cp < 16; ++cp)
#pragma unroll
            for (int c = 0; c < 16; ++c) {
                q[c]  += qn[cp] * wq[cp * 16 + c];
                kk[c] += hv[cp] * wk[cp * 16 + c];
            }
#pragma unroll
        for (int c = 0; c < 16; ++c) q[c] *= 0.25f;   // 1/sqrt(16)
#pragma unroll
        for (int i = 0; i < 4; ++i)
            *(float4*)&ks[r][kq][i * 4] =
                make_float4(kk[i * 4], kk[i * 4 + 1], kk[i * 4 + 2], kk[i * 4 + 3]);
        // xc0 = normalize(relu(h3)) per capsule — purely local
        float ss = 0.f;
        float rl[16];
#pragma unroll
        for (int c = 0; c < 16; ++c) { rl[c] = fmaxf(hv[c], 0.f); ss += rl[c] * rl[c]; }
        float inv = 1.f / fmaxf(sqrtf(ss), 1e-12f);
        float4* xo = (float4*)(xc0 + (size_t)row * D + kq * DD);
#pragma unroll
        for (int i = 0; i < 4; ++i)
            xo[i] = make_float4(rl[i * 4] * inv, rl[i * 4 + 1] * inv,
                                rl[i * 4 + 2] * inv, rl[i * 4 + 3] * inv);
    }
    __syncthreads();

    // ---- phase 3: scores row kq vs all 8 keys; softmax local; off-diag sum
    float offd = 0.f;
    if (row < n) {
        float s[8];
#pragma unroll
        for (int j = 0; j < 8; ++j) {
            float d = 0.f;
#pragma unroll
            for (int i = 0; i < 4; ++i) {
                float4 f = *(const float4*)&ks[r][j][i * 4];
                d += q[i * 4] * f.x + q[i * 4 + 1] * f.y
                   + q[i * 4 + 2] * f.z + q[i * 4 + 3] * f.w;
            }
            s[j] = d;
        }
        float mx = s[0];
#pragma unroll
        for (int j = 1; j < 8; ++j) mx = fmaxf(mx, s[j]);
        float e[8], se = 0.f;
#pragma unroll
        for (int j = 0; j < 8; ++j) { e[j] = __expf(s[j] - mx); se += e[j]; }
        float rse = 1.f / se;
#pragma unroll
        for (int j = 0; j < 8; ++j)
            if (j != kq) offd += e[j] * rse;
    }
    offd += __shfl_xor(offd, 1);
    offd += __shfl_xor(offd, 2);
    offd += __shfl_xor(offd, 4);
    offd += __shfl_xor(offd, 8);
    offd += __shfl_xor(offd, 16);
    offd += __shfl_xor(offd, 32);
    int lane = tid & 63, wid = tid >> 6;
    if (lane == 0) red[wid] = offd;
    __syncthreads();
    if (tid == 0) partial[blockIdx.x] = red[0] + red[1] + red[2] + red[3];
}

// ---------------------------------------------------------------- partial-sum reduce
__global__ __launch_bounds__(256) void reduce_kernel(
        const float* __restrict__ partial, float* __restrict__ acc, int npart) {
    __shared__ float red[4];
    const int t = threadIdx.x;
    float s = 0.f;
    for (int i = t; i < npart; i += 256) s += partial[i];
    s += __shfl_xor(s, 1);  s += __shfl_xor(s, 2);
    s += __shfl_xor(s, 4);  s += __shfl_xor(s, 8);
    s += __shfl_xor(s, 16); s += __shfl_xor(s, 32);
    if ((t & 63) == 0) red[t >> 6] = s;
    __syncthreads();
    if (t == 0) acc[0] = red[0] + red[1] + red[2] + red[3];
}

// ---------------------------------------------------------------- routing: ONE WAVE PER NODE
// (unchanged from R7 — measured DS-pipe-bound floor ~103 us; see journal)
template <bool LAST>
__global__ __launch_bounds__(64) void routing_kernel(
        const float* __restrict__ xc,   // (n+1)*128, normalized, row n = 0
        const int* __restrict__ nb,     // n*32
        float* __restrict__ out,        // LAST ? u1 : xc_next rows [0,n)
        int* __restrict__ amax, int n) {
    __shared__ alignas(16) float zs[M * D];         // 1024 xor-swizzled float4s
    __shared__ alignas(16) float u_s[NCAPS * 20];   // u[k][c] at k*20+c
    __shared__ alignas(16) float pT[NCAPS * 36];    // pT[k][m]
    const int l = threadIdx.x;
    const int v = blockIdx.x;
    const int m  = l & 31;
    const int kh = l >> 5;
    const int f4 = m;
    const int mg = kh;

    {
        int sm = l >> 1, sh = l & 1;
        int src = 0;
        if (l < M) {
            int nbv = nb[(size_t)v * M + l];
            src = (nbv < 0) ? n : nbv;
        }
        int srow = __shfl(src, sm);
        const float4* g = (const float4*)(xc + (size_t)srow * D);
#pragma unroll
        for (int i = 0; i < 16; ++i) {
            int f = sh * 16 + i;
            ((float4*)zs)[sm * 32 + (f ^ sm)] = g[f];
        }
    }
    float4 x3 = ((const float4*)(xc + (size_t)v * D))[f4];
    __syncthreads();

    {
        float4 a = make_float4(0.f, 0.f, 0.f, 0.f);
#pragma unroll
        for (int j = 0; j < 16; ++j) {
            int r = mg * 16 + j;
            float4 zf = ((const float4*)zs)[r * 32 + (f4 ^ r)];
            a.x += zf.x; a.y += zf.y; a.z += zf.z; a.w += zf.w;
        }
        a.x += __shfl_xor(a.x, 32); a.y += __shfl_xor(a.y, 32);
        a.z += __shfl_xor(a.z, 32); a.w += __shfl_xor(a.w, 32);
        a.x = a.x * 0.125f + x3.x;  a.y = a.y * 0.125f + x3.y;
        a.z = a.z * 0.125f + x3.z;  a.w = a.w * 0.125f + x3.w;
        float ss = a.x * a.x + a.y * a.y + a.z * a.z + a.w * a.w;
        ss += __shfl_xor(ss, 1); ss += __shfl_xor(ss, 2);
        float inv = 1.f / fmaxf(sqrtf(ss), 1e-12f);
        if (l < 32)
            *(float4*)&u_s[(f4 >> 2) * 20 + (f4 & 3) * 4] =
                make_float4(a.x * inv, a.y * inv, a.z * inv, a.w * inv);
    }
    __syncthreads();

    for (int it = 1; it < ROUTIT; ++it) {
        float pr[4];
#pragma unroll
        for (int j = 0; j < 4; ++j) {
            float s = 0.f;
#pragma unroll
            for (int c4 = 0; c4 < 4; ++c4) {
                int f = kh * 16 + j * 4 + c4;
                float4 zf = ((const float4*)zs)[m * 32 + (f ^ m)];
                float4 uf = *(const float4*)&u_s[(kh * 4 + j) * 20 + c4 * 4];
                s += zf.x * uf.x + zf.y * uf.y + zf.z * uf.z + zf.w * uf.w;
            }
            pr[j] = s;
        }
        float po[4];
#pragma unroll
        for (int j = 0; j < 4; ++j) po[j] = __shfl_xor(pr[j], 32);
        if (LAST && it == ROUTIT - 1) {
            float p8[8];
#pragma unroll
            for (int j = 0; j < 4; ++j) {
                p8[kh * 4 + j] = pr[j];
                p8[(kh ^ 1) * 4 + j] = po[j];
            }
            float bv = p8[0]; int bi = 0;
#pragma unroll
            for (int k2 = 1; k2 < 8; ++k2)
                if (p8[k2] > bv) { bv = p8[k2]; bi = k2; }
            if (l < 32) amax[(size_t)v * M + m] = bi;
        }
        float er[4], S = 0.f;
#pragma unroll
        for (int j = 0; j < 4; ++j) { er[j] = __expf(pr[j]); S += er[j]; }
#pragma unroll
        for (int j = 0; j < 4; ++j) S += __expf(po[j]);
        float rS = 1.f / S;
#pragma unroll
        for (int j = 0; j < 4; ++j)
            pT[(kh * 4 + j) * 36 + m] = er[j] * rS;
        __syncthreads();

        float pk[16];
        {
            const int k2 = f4 >> 2;
#pragma unroll
            for (int j4 = 0; j4 < 4; ++j4) {
                float4 pp = *(const float4*)&pT[k2 * 36 + mg * 16 + j4 * 4];
                pk[j4 * 4 + 0] = pp.x; pk[j4 * 4 + 1] = pp.y;
                pk[j4 * 4 + 2] = pp.z; pk[j4 * 4 + 3] = pp.w;
            }
        }
        float4 a = make_float4(0.f, 0.f, 0.f, 0.f);
#pragma unroll
        for (int j = 0; j < 16; ++j) {
            int r = mg * 16 + j;
            float4 zf = ((const float4*)zs)[r * 32 + (f4 ^ r)];
            a.x += zf.x * pk[j]; a.y += zf.y * pk[j];
            a.z += zf.z * pk[j]; a.w += zf.w * pk[j];
        }
        a.x += __shfl_xor(a.x, 32); a.y += __shfl_xor(a.y, 32);
        a.z += __shfl_xor(a.z, 32); a.w += __shfl_xor(a.w, 32);
        a.x += x3.x; a.y += x3.y; a.z += x3.z; a.w += x3.w;

        if (it < ROUTIT - 1) {
            float ss = a.x * a.x + a.y * a.y + a.z * a.z + a.w * a.w;
            ss += __shfl_xor(ss, 1); ss += __shfl_xor(ss, 2);
            float inv = 1.f / fmaxf(sqrtf(ss), 1e-12f);
            if (l < 32)
                *(float4*)&u_s[(f4 >> 2) * 20 + (f4 & 3) * 4] =
                    make_float4(a.x * inv, a.y * inv, a.z * inv, a.w * inv);
            __syncthreads();
        } else if (LAST) {
            if (l < 32) ((float4*)(out + (size_t)v * D))[f4] = a;
        } else {
            float r0 = fmaxf(a.x, 0.f), r1 = fmaxf(a.y, 0.f);
            float r2 = fmaxf(a.z, 0.f), r3 = fmaxf(a.w, 0.f);
            float ss = r0 * r0 + r1 * r1 + r2 * r2 + r3 * r3;
            ss += __shfl_xor(ss, 1); ss += __shfl_xor(ss, 2);
            float inv = 1.f / fmaxf(sqrtf(ss), 1e-12f);
            if (l < 32)
                ((float4*)(out + (size_t)v * D))[f4] =
                    make_float4(r0 * inv, r1 * inv, r2 * inv, r3 * inv);
        }
    }
}

// ---------------------------------------------------------------- second-hop presum
// s2[w][c] = sum_{b<5} xc1[nbm[w,b]][amax[w,b]*16 + c] — depends only on w.
__global__ __launch_bounds__(256) void s2_kernel(
        const float* __restrict__ xc1, const int* __restrict__ nb,
        const int* __restrict__ amax, float* __restrict__ s2, int n) {
    int idx = blockIdx.x * 256 + threadIdx.x;
    if (idx >= n * 16) return;
    int w = idx >> 4, c = idx & 15;
    float s = 0.f;
#pragma unroll
    for (int b = 0; b < CUT; ++b) {
        int t  = nb[(size_t)w * M + b];
        int jj = amax[(size_t)w * M + b];
        int im = (t < 0) ? n : t;   // row n = zeros
        s += xc1[(size_t)im * D + jj * DD + c];
    }
    s2[idx] = s;
}

// ---------------------------------------------------------------- meta gather + MLP + log_softmax
__global__ __launch_bounds__(256) void meta_kernel(
        const float* __restrict__ u1, const float* __restrict__ s2,
        const int* __restrict__ nb, const int* __restrict__ amax,
        const float* __restrict__ mlp_w, const float* __restrict__ mlp_b,
        const float* __restrict__ attn_acc, float* __restrict__ d_out, int n) {
    __shared__ float Wl[128 * 16];
    __shared__ float accs[16][132];
    const int t = threadIdx.x;
#pragma unroll
    for (int i = 0; i < 8; ++i) Wl[t + i * 256] = mlp_w[t + i * 256];
    const int g = t >> 4, c = t & 15;
    const int v = blockIdx.x * 16 + g;
    if (blockIdx.x == 0 && t == 0)
        d_out[(size_t)n * 16] = attn_acc[0] * (1.f / (56.f * (float)n));
    if (v < n) {
#pragma unroll
        for (int i = 0; i < 8; ++i) accs[g][i * 16 + c] = 0.f;
        for (int a = 0; a < CUT; ++a) {
            int w = nb[(size_t)v * M + a];
            if (w < 0) continue;
            int i = amax[(size_t)v * M + a];   // first-hop capsule
            accs[g][i * 16 + c] += s2[(size_t)w * 16 + c];
        }
#pragma unroll
        for (int i = 0; i < 8; ++i) {
            float meta = u1[(size_t)v * D + i * 16 + c] + accs[g][i * 16 + c] * (1.f / 25.f);
            accs[g][i * 16 + c] = fmaxf(meta, 0.f);
        }
    }
    __syncthreads();
    if (v < n) {
        float o = mlp_b[c];
#pragma unroll
        for (int dd = 0; dd < 128; ++dd) o += accs[g][dd] * Wl[dd * 16 + c];
        float mx = o;
        mx = fmaxf(mx, __shfl_xor(mx, 1));
        mx = fmaxf(mx, __shfl_xor(mx, 2));
        mx = fmaxf(mx, __shfl_xor(mx, 4));
        mx = fmaxf(mx, __shfl_xor(mx, 8));
        float e = __expf(o - mx);
        float se = wred16_sum(e);
        float ls = (o - mx) - logf(se);
        d_out[(size_t)v * 16 + c] = ls;
        d_out[(size_t)n * 16 + 1 + (size_t)v * 16 + c] = o;
    }
}

// ---------------------------------------------------------------- launch
extern "C" void kernel_launch(void* const* d_in, const int* in_sizes, int n_in,
                              void* d_out, int out_size, void* d_ws, size_t ws_size,
                              hipStream_t stream) {
    const float* x     = (const float*)d_in[0];
    const int*   nb    = (const int*)d_in[1];
    const float* pca_w = (const float*)d_in[2];
    const float* pca_b = (const float*)d_in[3];
    const float* ln_g  = (const float*)d_in[4];
    const float* ln_b  = (const float*)d_in[5];
    const float* w_qs  = (const float*)d_in[6];
    const float* w_ks  = (const float*)d_in[7];
    const float* mlp_w = (const float*)d_in[8];
    const float* mlp_b = (const float*)d_in[9];
    float* out = (float*)d_out;

    const int d = 128;
    const int nfeat = in_sizes[2] / d;      // 500
    const int n = in_sizes[0] / nfeat;      // 20000
    const int nblk = (n + 31) / 32;         // fused pca_attn blocks (625)

    float* bufA = (float*)d_ws;                       // n*128 : u1
    float* bufB = bufA + (size_t)n * d;               // (n+1)*128 : xc0; later amax+s2
    float* bufC = bufB + (size_t)(n + 1) * d;         // (n+1)*128 : xc1
    float* acc  = bufC + (size_t)(n + 1) * d;         // 1 float : attn loss sum
    int* amax = (int*)bufB;                           // n*32 ints (xc0 dead)
    float* s2 = bufB + (size_t)n * M;                 // n*16 floats, after amax
    // attn partials overlay the head of bufC: consumed by reduce_kernel
    // before routing<false> writes bufC; row n untouched.
    float* partial = bufC;

    init_kernel<<<1, 256, 0, stream>>>(bufB, bufC, n);
    pca_attn<<<nblk, 256, 0, stream>>>(x, pca_w, pca_b, ln_g, ln_b, w_qs, w_ks,
                                       bufB, partial, n, nfeat);
    reduce_kernel<<<1, 256, 0, stream>>>(partial, acc, nblk);
    routing_kernel<false><<<n, 64, 0, stream>>>(bufB, nb, bufC, nullptr, n);
    routing_kernel<true><<<n, 64, 0, stream>>>(bufC, nb, bufA, amax, n);
    s2_kernel<<<(n * 16 + 255) / 256, 256, 0, stream>>>(bufC, nb, amax, s2, n);
    meta_kernel<<<(n + 15) / 16, 256, 0, stream>>>(bufA, s2, nb, amax, mlp_w, mlp_b, acc, out, n);
}

// Round 10
// 310.171 us; speedup vs baseline: 1.2639x; 1.1026x over previous
//
#include <hip/hip_runtime.h>
#include <math.h>

#define NCAPS 8
#define DD    16
#define D     128
#define M     32
#define ROUTIT 6
#define CUT   5

__device__ __forceinline__ float wred16_sum(float v) {
    v += __shfl_xor(v, 1);
    v += __shfl_xor(v, 2);
    v += __shfl_xor(v, 4);
    v += __shfl_xor(v, 8);
    return v;
}

// pack two floats -> bf16x2 (round-to-nearest-even)
__device__ __forceinline__ unsigned int pack_bf2(float a, float b) {
    unsigned int ua = __float_as_uint(a);
    ua += 0x7fffu + ((ua >> 16) & 1u);
    unsigned int ub = __float_as_uint(b);
    ub += 0x7fffu + ((ub >> 16) & 1u);
    return (ua >> 16) | (ub & 0xffff0000u);
}
__device__ __forceinline__ float2 unpack_bf2(unsigned int u) {
    return make_float2(__uint_as_float(u << 16),
                       __uint_as_float(u & 0xffff0000u));
}

// ---------------------------------------------------------------- init
__global__ void init_kernel(float* xc0, float* xc1, int n) {
    int t = threadIdx.x;
    if (t < D) {
        xc0[(size_t)n * D + t] = 0.f;   // dummy row n = 0
        xc1[(size_t)n * D + t] = 0.f;
    }
}

// ---------------------------------------------------------------- fused PCA GEMM + attn loss + xc0
// (unchanged from R9 — vectorized staging)
__global__ __launch_bounds__(256) void pca_attn(
        const float* __restrict__ x, const float* __restrict__ w,
        const float* __restrict__ bias, const float* __restrict__ ln_g,
        const float* __restrict__ ln_b, const float* __restrict__ w_qs,
        const float* __restrict__ w_ks, float* __restrict__ xc0,
        float* __restrict__ partial, int n, int nfeat) {
    __shared__ float xs[20][36];                  // [kk][r]
    __shared__ alignas(16) float ws[20][128];     // [kk][col]
    __shared__ alignas(16) float hs[32][132];     // h tile, +4 pad
    __shared__ alignas(16) float ks[32][8][20];   // kk vectors, f4-aligned rows
    __shared__ float wq[256], wk[256];
    __shared__ float red[4];
    const int tid = threadIdx.x;
    const int cg = tid & 31;
    const int rg = tid >> 5;
    const int row0 = blockIdx.x * 32;
    wq[tid] = w_qs[tid];
    wk[tid] = w_ks[tid];
    const float4 bi4 = *(const float4*)&bias[cg * 4];

    // ---- phase 1: GEMM (BM=32, BN=128, BK=20, 4x4 microtile)
    float acc[4][4] = {};
    for (int k0 = 0; k0 < nfeat; k0 += 20) {
        if (tid < 160) {
            int r = tid / 5, cf = tid % 5;
            int row = row0 + r;
            float4 f = (row < n)
                ? *(const float4*)&x[(size_t)row * nfeat + k0 + cf * 4]
                : make_float4(0.f, 0.f, 0.f, 0.f);
            xs[cf * 4 + 0][r] = f.x; xs[cf * 4 + 1][r] = f.y;
            xs[cf * 4 + 2][r] = f.z; xs[cf * 4 + 3][r] = f.w;
        }
#pragma unroll
        for (int i = 0; i < 3; ++i) {
            int f = tid + i * 256;
            if (f < 640) {
                int kk = f >> 5, c4 = f & 31;
                *(float4*)&ws[kk][c4 * 4] =
                    *(const float4*)&w[(size_t)(k0 + kk) * 128 + c4 * 4];
            }
        }
        __syncthreads();
#pragma unroll
        for (int kk = 0; kk < 20; ++kk) {
            float4 a = *(const float4*)&xs[kk][rg * 4];
            float4 b = *(const float4*)&ws[kk][cg * 4];
            float av[4] = {a.x, a.y, a.z, a.w};
            float bv[4] = {b.x, b.y, b.z, b.w};
#pragma unroll
            for (int i = 0; i < 4; ++i)
#pragma unroll
                for (int j = 0; j < 4; ++j) acc[i][j] += av[i] * bv[j];
        }
        __syncthreads();
    }
#pragma unroll
    for (int i = 0; i < 4; ++i)
        *(float4*)&hs[rg * 4 + i][cg * 4] =
            make_float4(acc[i][0] + bi4.x, acc[i][1] + bi4.y,
                        acc[i][2] + bi4.z, acc[i][3] + bi4.w);
    __syncthreads();

    // ---- phase 2: per-(row, capsule) LN + q/kk matmuls + xc0
    const int r = tid >> 3, kq = tid & 7;
    const int row = row0 + r;
    float hv[16], q[16], kk[16];
    if (row < n) {
#pragma unroll
        for (int i = 0; i < 4; ++i) {
            float4 f = *(const float4*)&hs[r][kq * 16 + i * 4];
            hv[i * 4 + 0] = f.x; hv[i * 4 + 1] = f.y;
            hv[i * 4 + 2] = f.z; hv[i * 4 + 3] = f.w;
        }
        float mu = 0.f;
#pragma unroll
        for (int c = 0; c < 16; ++c) mu += hv[c];
        mu *= (1.f / 16.f);
        float var = 0.f;
#pragma unroll
        for (int c = 0; c < 16; ++c) { float d = hv[c] - mu; var += d * d; }
        var *= (1.f / 16.f);
        float rstd = rsqrtf(var + 1e-6f);
        float qn[16];
#pragma unroll
        for (int c = 0; c < 16; ++c)
            qn[c] = (hv[c] - mu) * rstd * ln_g[c] + ln_b[c];
#pragma unroll
        for (int c = 0; c < 16; ++c) { q[c] = 0.f; kk[c] = 0.f; }
#pragma unroll
        for (int cp = 0; cp < 16; ++cp)
#pragma unroll
            for (int c = 0; c < 16; ++c) {
                q[c]  += qn[cp] * wq[cp * 16 + c];
                kk[c] += hv[cp] * wk[cp * 16 + c];
            }
#pragma unroll
        for (int c = 0; c < 16; ++c) q[c] *= 0.25f;   // 1/sqrt(16)
#pragma unroll
        for (int i = 0; i < 4; ++i)
            *(float4*)&ks[r][kq][i * 4] =
                make_float4(kk[i * 4], kk[i * 4 + 1], kk[i * 4 + 2], kk[i * 4 + 3]);
        float ss = 0.f;
        float rl[16];
#pragma unroll
        for (int c = 0; c < 16; ++c) { rl[c] = fmaxf(hv[c], 0.f); ss += rl[c] * rl[c]; }
        float inv = 1.f / fmaxf(sqrtf(ss), 1e-12f);
        float4* xo = (float4*)(xc0 + (size_t)row * D + kq * DD);
#pragma unroll
        for (int i = 0; i < 4; ++i)
            xo[i] = make_float4(rl[i * 4] * inv, rl[i * 4 + 1] * inv,
                                rl[i * 4 + 2] * inv, rl[i * 4 + 3] * inv);
    }
    __syncthreads();

    // ---- phase 3: scores row kq vs all 8 keys; softmax; off-diag sum
    float offd = 0.f;
    if (row < n) {
        float s[8];
#pragma unroll
        for (int j = 0; j < 8; ++j) {
            float d = 0.f;
#pragma unroll
            for (int i = 0; i < 4; ++i) {
                float4 f = *(const float4*)&ks[r][j][i * 4];
                d += q[i * 4] * f.x + q[i * 4 + 1] * f.y
                   + q[i * 4 + 2] * f.z + q[i * 4 + 3] * f.w;
            }
            s[j] = d;
        }
        float mx = s[0];
#pragma unroll
        for (int j = 1; j < 8; ++j) mx = fmaxf(mx, s[j]);
        float e[8], se = 0.f;
#pragma unroll
        for (int j = 0; j < 8; ++j) { e[j] = __expf(s[j] - mx); se += e[j]; }
        float rse = 1.f / se;
#pragma unroll
        for (int j = 0; j < 8; ++j)
            if (j != kq) offd += e[j] * rse;
    }
    offd += __shfl_xor(offd, 1);
    offd += __shfl_xor(offd, 2);
    offd += __shfl_xor(offd, 4);
    offd += __shfl_xor(offd, 8);
    offd += __shfl_xor(offd, 16);
    offd += __shfl_xor(offd, 32);
    int lane = tid & 63, wid = tid >> 6;
    if (lane == 0) red[wid] = offd;
    __syncthreads();
    if (tid == 0) partial[blockIdx.x] = red[0] + red[1] + red[2] + red[3];
}

// ---------------------------------------------------------------- partial-sum reduce
__global__ __launch_bounds__(256) void reduce_kernel(
        const float* __restrict__ partial, float* __restrict__ acc, int npart) {
    __shared__ float red[4];
    const int t = threadIdx.x;
    float s = 0.f;
    for (int i = t; i < npart; i += 256) s += partial[i];
    s += __shfl_xor(s, 1);  s += __shfl_xor(s, 2);
    s += __shfl_xor(s, 4);  s += __shfl_xor(s, 8);
    s += __shfl_xor(s, 16); s += __shfl_xor(s, 32);
    if ((t & 63) == 0) red[t >> 6] = s;
    __syncthreads();
    if (t == 0) acc[0] = red[0] + red[1] + red[2] + red[3];
}

// ---------------------------------------------------------------- routing: ONE WAVE PER NODE, bf16 z
// R10: z packed bf16x2 in LDS (8 KB vs 16 KB). Halves DS-pipe bytes AND
// doubles blocks/CU (LDS was the occupancy cap at 2 waves/SIMD). z elements
// are unit-norm components (|z|<=1): bf16 RNE error <=0.002/elem; argmax
// flips are benign (~0.003 in final logits). u_s/pT/x3 stay f32.
// Same xor-swizzled slot layout (slot f = channels 4f..4f+3, now uint2).
template <bool LAST>
__global__ __launch_bounds__(64) void routing_kernel(
        const float* __restrict__ xc,   // (n+1)*128, normalized, row n = 0
        const int* __restrict__ nb,     // n*32
        float* __restrict__ out,        // LAST ? u1 : xc_next rows [0,n)
        int* __restrict__ amax, int n) {
    __shared__ alignas(16) uint2 zsu[M * 32];       // bf16x4 per slot, 8 KB
    __shared__ alignas(16) float u_s[NCAPS * 20];   // u[k][c] at k*20+c
    __shared__ alignas(16) float pT[NCAPS * 36];    // pT[k][m]
    const int l = threadIdx.x;
    const int v = blockIdx.x;
    const int m  = l & 31;
    const int kh = l >> 5;
    const int f4 = m;
    const int mg = kh;

    {
        int sm = l >> 1, sh = l & 1;
        int src = 0;
        if (l < M) {
            int nbv = nb[(size_t)v * M + l];
            src = (nbv < 0) ? n : nbv;
        }
        int srow = __shfl(src, sm);
        const float4* g = (const float4*)(xc + (size_t)srow * D);
#pragma unroll
        for (int i = 0; i < 16; ++i) {
            int f = sh * 16 + i;
            float4 zf = g[f];
            zsu[sm * 32 + (f ^ sm)] =
                make_uint2(pack_bf2(zf.x, zf.y), pack_bf2(zf.z, zf.w));
        }
    }
    float4 x3 = ((const float4*)(xc + (size_t)v * D))[f4];
    __syncthreads();

    // ---- it 0: p uniform = 1/8
    {
        float4 a = make_float4(0.f, 0.f, 0.f, 0.f);
#pragma unroll
        for (int j = 0; j < 16; ++j) {
            int r = mg * 16 + j;
            uint2 zz = zsu[r * 32 + (f4 ^ r)];
            float2 lo = unpack_bf2(zz.x), hi = unpack_bf2(zz.y);
            a.x += lo.x; a.y += lo.y; a.z += hi.x; a.w += hi.y;
        }
        a.x += __shfl_xor(a.x, 32); a.y += __shfl_xor(a.y, 32);
        a.z += __shfl_xor(a.z, 32); a.w += __shfl_xor(a.w, 32);
        a.x = a.x * 0.125f + x3.x;  a.y = a.y * 0.125f + x3.y;
        a.z = a.z * 0.125f + x3.z;  a.w = a.w * 0.125f + x3.w;
        float ss = a.x * a.x + a.y * a.y + a.z * a.z + a.w * a.w;
        ss += __shfl_xor(ss, 1); ss += __shfl_xor(ss, 2);
        float inv = 1.f / fmaxf(sqrtf(ss), 1e-12f);
        if (l < 32)
            *(float4*)&u_s[(f4 >> 2) * 20 + (f4 & 3) * 4] =
                make_float4(a.x * inv, a.y * inv, a.z * inv, a.w * inv);
    }
    __syncthreads();

    for (int it = 1; it < ROUTIT; ++it) {
        // ---- p-step: lane (m, kh) computes p for k = kh*4+j
        float pr[4];
#pragma unroll
        for (int j = 0; j < 4; ++j) {
            float s = 0.f;
#pragma unroll
            for (int c2 = 0; c2 < 4; ++c2) {
                int f = kh * 16 + j * 4 + c2;
                uint2 zz = zsu[m * 32 + (f ^ m)];
                float2 lo = unpack_bf2(zz.x), hi = unpack_bf2(zz.y);
                float4 uf = *(const float4*)&u_s[(kh * 4 + j) * 20 + c2 * 4];
                s += lo.x * uf.x + lo.y * uf.y + hi.x * uf.z + hi.y * uf.w;
            }
            pr[j] = s;
        }
        float po[4];
#pragma unroll
        for (int j = 0; j < 4; ++j) po[j] = __shfl_xor(pr[j], 32);
        if (LAST && it == ROUTIT - 1) {
            float p8[8];
#pragma unroll
            for (int j = 0; j < 4; ++j) {
                p8[kh * 4 + j] = pr[j];
                p8[(kh ^ 1) * 4 + j] = po[j];
            }
            float bv = p8[0]; int bi = 0;
#pragma unroll
            for (int k2 = 1; k2 < 8; ++k2)
                if (p8[k2] > bv) { bv = p8[k2]; bi = k2; }
            if (l < 32) amax[(size_t)v * M + m] = bi;
        }
        // |p| <= 1 -> max-free softmax
        float er[4], S = 0.f;
#pragma unroll
        for (int j = 0; j < 4; ++j) { er[j] = __expf(pr[j]); S += er[j]; }
#pragma unroll
        for (int j = 0; j < 4; ++j) S += __expf(po[j]);
        float rS = 1.f / S;
#pragma unroll
        for (int j = 0; j < 4; ++j)
            pT[(kh * 4 + j) * 36 + m] = er[j] * rS;
        __syncthreads();

        // ---- u-step: lane (f4, mg) sums 16 rows
        float pk[16];
        {
            const int k2 = f4 >> 2;
#pragma unroll
            for (int j4 = 0; j4 < 4; ++j4) {
                float4 pp = *(const float4*)&pT[k2 * 36 + mg * 16 + j4 * 4];
                pk[j4 * 4 + 0] = pp.x; pk[j4 * 4 + 1] = pp.y;
                pk[j4 * 4 + 2] = pp.z; pk[j4 * 4 + 3] = pp.w;
            }
        }
        float4 a = make_float4(0.f, 0.f, 0.f, 0.f);
#pragma unroll
        for (int j = 0; j < 16; ++j) {
            int r = mg * 16 + j;
            uint2 zz = zsu[r * 32 + (f4 ^ r)];
            float2 lo = unpack_bf2(zz.x), hi = unpack_bf2(zz.y);
            a.x += lo.x * pk[j]; a.y += lo.y * pk[j];
            a.z += hi.x * pk[j]; a.w += hi.y * pk[j];
        }
        a.x += __shfl_xor(a.x, 32); a.y += __shfl_xor(a.y, 32);
        a.z += __shfl_xor(a.z, 32); a.w += __shfl_xor(a.w, 32);
        a.x += x3.x; a.y += x3.y; a.z += x3.z; a.w += x3.w;

        if (it < ROUTIT - 1) {
            float ss = a.x * a.x + a.y * a.y + a.z * a.z + a.w * a.w;
            ss += __shfl_xor(ss, 1); ss += __shfl_xor(ss, 2);
            float inv = 1.f / fmaxf(sqrtf(ss), 1e-12f);
            if (l < 32)
                *(float4*)&u_s[(f4 >> 2) * 20 + (f4 & 3) * 4] =
                    make_float4(a.x * inv, a.y * inv, a.z * inv, a.w * inv);
            __syncthreads();
        } else if (LAST) {
            if (l < 32) ((float4*)(out + (size_t)v * D))[f4] = a;
        } else {
            float r0 = fmaxf(a.x, 0.f), r1 = fmaxf(a.y, 0.f);
            float r2 = fmaxf(a.z, 0.f), r3 = fmaxf(a.w, 0.f);
            float ss = r0 * r0 + r1 * r1 + r2 * r2 + r3 * r3;
            ss += __shfl_xor(ss, 1); ss += __shfl_xor(ss, 2);
            float inv = 1.f / fmaxf(sqrtf(ss), 1e-12f);
            if (l < 32)
                ((float4*)(out + (size_t)v * D))[f4] =
                    make_float4(r0 * inv, r1 * inv, r2 * inv, r3 * inv);
        }
    }
}

// ---------------------------------------------------------------- second-hop presum
__global__ __launch_bounds__(256) void s2_kernel(
        const float* __restrict__ xc1, const int* __restrict__ nb,
        const int* __restrict__ amax, float* __restrict__ s2, int n) {
    int idx = blockIdx.x * 256 + threadIdx.x;
    if (idx >= n * 16) return;
    int w = idx >> 4, c = idx & 15;
    float s = 0.f;
#pragma unroll
    for (int b = 0; b < CUT; ++b) {
        int t  = nb[(size_t)w * M + b];
        int jj = amax[(size_t)w * M + b];
        int im = (t < 0) ? n : t;   // row n = zeros
        s += xc1[(size_t)im * D + jj * DD + c];
    }
    s2[idx] = s;
}

// ---------------------------------------------------------------- meta gather + MLP + log_softmax
__global__ __launch_bounds__(256) void meta_kernel(
        const float* __restrict__ u1, const float* __restrict__ s2,
        const int* __restrict__ nb, const int* __restrict__ amax,
        const float* __restrict__ mlp_w, const float* __restrict__ mlp_b,
        const float* __restrict__ attn_acc, float* __restrict__ d_out, int n) {
    __shared__ float Wl[128 * 16];
    __shared__ float accs[16][132];
    const int t = threadIdx.x;
#pragma unroll
    for (int i = 0; i < 8; ++i) Wl[t + i * 256] = mlp_w[t + i * 256];
    const int g = t >> 4, c = t & 15;
    const int v = blockIdx.x * 16 + g;
    if (blockIdx.x == 0 && t == 0)
        d_out[(size_t)n * 16] = attn_acc[0] * (1.f / (56.f * (float)n));
    if (v < n) {
#pragma unroll
        for (int i = 0; i < 8; ++i) accs[g][i * 16 + c] = 0.f;
        for (int a = 0; a < CUT; ++a) {
            int w = nb[(size_t)v * M + a];
            if (w < 0) continue;
            int i = amax[(size_t)v * M + a];   // first-hop capsule
            accs[g][i * 16 + c] += s2[(size_t)w * 16 + c];
        }
#pragma unroll
        for (int i = 0; i < 8; ++i) {
            float meta = u1[(size_t)v * D + i * 16 + c] + accs[g][i * 16 + c] * (1.f / 25.f);
            accs[g][i * 16 + c] = fmaxf(meta, 0.f);
        }
    }
    __syncthreads();
    if (v < n) {
        float o = mlp_b[c];
#pragma unroll
        for (int dd = 0; dd < 128; ++dd) o += accs[g][dd] * Wl[dd * 16 + c];
        float mx = o;
        mx = fmaxf(mx, __shfl_xor(mx, 1));
        mx = fmaxf(mx, __shfl_xor(mx, 2));
        mx = fmaxf(mx, __shfl_xor(mx, 4));
        mx = fmaxf(mx, __shfl_xor(mx, 8));
        float e = __expf(o - mx);
        float se = wred16_sum(e);
        float ls = (o - mx) - logf(se);
        d_out[(size_t)v * 16 + c] = ls;
        d_out[(size_t)n * 16 + 1 + (size_t)v * 16 + c] = o;
    }
}

// ---------------------------------------------------------------- launch
extern "C" void kernel_launch(void* const* d_in, const int* in_sizes, int n_in,
                              void* d_out, int out_size, void* d_ws, size_t ws_size,
                              hipStream_t stream) {
    const float* x     = (const float*)d_in[0];
    const int*   nb    = (const int*)d_in[1];
    const float* pca_w = (const float*)d_in[2];
    const float* pca_b = (const float*)d_in[3];
    const float* ln_g  = (const float*)d_in[4];
    const float* ln_b  = (const float*)d_in[5];
    const float* w_qs  = (const float*)d_in[6];
    const float* w_ks  = (const float*)d_in[7];
    const float* mlp_w = (const float*)d_in[8];
    const float* mlp_b = (const float*)d_in[9];
    float* out = (float*)d_out;

    const int d = 128;
    const int nfeat = in_sizes[2] / d;      // 500
    const int n = in_sizes[0] / nfeat;      // 20000
    const int nblk = (n + 31) / 32;         // fused pca_attn blocks (625)

    float* bufA = (float*)d_ws;                       // n*128 : u1
    float* bufB = bufA + (size_t)n * d;               // (n+1)*128 : xc0; later amax+s2
    float* bufC = bufB + (size_t)(n + 1) * d;         // (n+1)*128 : xc1
    float* acc  = bufC + (size_t)(n + 1) * d;         // 1 float : attn loss sum
    int* amax = (int*)bufB;                           // n*32 ints (xc0 dead)
    float* s2 = bufB + (size_t)n * M;                 // n*16 floats, after amax
    float* partial = bufC;                            // overlay, consumed pre-routing

    init_kernel<<<1, 256, 0, stream>>>(bufB, bufC, n);
    pca_attn<<<nblk, 256, 0, stream>>>(x, pca_w, pca_b, ln_g, ln_b, w_qs, w_ks,
                                       bufB, partial, n, nfeat);
    reduce_kernel<<<1, 256, 0, stream>>>(partial, acc, nblk);
    routing_kernel<false><<<n, 64, 0, stream>>>(bufB, nb, bufC, nullptr, n);
    routing_kernel<true><<<n, 64, 0, stream>>>(bufC, nb, bufA, amax, n);
    s2_kernel<<<(n * 16 + 255) / 256, 256, 0, stream>>>(bufC, nb, amax, s2, n);
    meta_kernel<<<(n + 15) / 16, 256, 0, stream>>>(bufA, s2, nb, amax, mlp_w, mlp_b, acc, out, n);
}

// Round 11
// 286.648 us; speedup vs baseline: 1.3676x; 1.0821x over previous
//
#include <hip/hip_runtime.h>
#include <math.h>

#define NCAPS 8
#define DD    16
#define D     128
#define M     32
#define ROUTIT 6
#define CUT   5

__device__ __forceinline__ float wred16_sum(float v) {
    v += __shfl_xor(v, 1);
    v += __shfl_xor(v, 2);
    v += __shfl_xor(v, 4);
    v += __shfl_xor(v, 8);
    return v;
}

// ---- f16 pair pack/unpack (RNE via default float->_Float16 conversion)
typedef _Float16 h2 __attribute__((ext_vector_type(2)));
union U32H2 { unsigned u; h2 h; };
__device__ __forceinline__ unsigned pack_h2(float a, float b) {
    U32H2 r; r.h.x = (_Float16)a; r.h.y = (_Float16)b; return r.u;
}
__device__ __forceinline__ h2 ash2(unsigned u) { U32H2 r; r.u = u; return r.h; }

// ---------------------------------------------------------------- init
__global__ void init_kernel(float* xc0, float* xc1, int n) {
    int t = threadIdx.x;
    if (t < D) {
        xc0[(size_t)n * D + t] = 0.f;   // dummy row n = 0
        xc1[(size_t)n * D + t] = 0.f;
    }
}

// ---------------------------------------------------------------- fused PCA GEMM + attn loss + xc0
// (unchanged from R9 — vectorized staging)
__global__ __launch_bounds__(256) void pca_attn(
        const float* __restrict__ x, const float* __restrict__ w,
        const float* __restrict__ bias, const float* __restrict__ ln_g,
        const float* __restrict__ ln_b, const float* __restrict__ w_qs,
        const float* __restrict__ w_ks, float* __restrict__ xc0,
        float* __restrict__ partial, int n, int nfeat) {
    __shared__ float xs[20][36];                  // [kk][r]
    __shared__ alignas(16) float ws[20][128];     // [kk][col]
    __shared__ alignas(16) float hs[32][132];     // h tile, +4 pad
    __shared__ alignas(16) float ks[32][8][20];   // kk vectors, f4-aligned rows
    __shared__ float wq[256], wk[256];
    __shared__ float red[4];
    const int tid = threadIdx.x;
    const int cg = tid & 31;
    const int rg = tid >> 5;
    const int row0 = blockIdx.x * 32;
    wq[tid] = w_qs[tid];
    wk[tid] = w_ks[tid];
    const float4 bi4 = *(const float4*)&bias[cg * 4];

    float acc[4][4] = {};
    for (int k0 = 0; k0 < nfeat; k0 += 20) {
        if (tid < 160) {
            int r = tid / 5, cf = tid % 5;
            int row = row0 + r;
            float4 f = (row < n)
                ? *(const float4*)&x[(size_t)row * nfeat + k0 + cf * 4]
                : make_float4(0.f, 0.f, 0.f, 0.f);
            xs[cf * 4 + 0][r] = f.x; xs[cf * 4 + 1][r] = f.y;
            xs[cf * 4 + 2][r] = f.z; xs[cf * 4 + 3][r] = f.w;
        }
#pragma unroll
        for (int i = 0; i < 3; ++i) {
            int f = tid + i * 256;
            if (f < 640) {
                int kk = f >> 5, c4 = f & 31;
                *(float4*)&ws[kk][c4 * 4] =
                    *(const float4*)&w[(size_t)(k0 + kk) * 128 + c4 * 4];
            }
        }
        __syncthreads();
#pragma unroll
        for (int kk = 0; kk < 20; ++kk) {
            float4 a = *(const float4*)&xs[kk][rg * 4];
            float4 b = *(const float4*)&ws[kk][cg * 4];
            float av[4] = {a.x, a.y, a.z, a.w};
            float bv[4] = {b.x, b.y, b.z, b.w};
#pragma unroll
            for (int i = 0; i < 4; ++i)
#pragma unroll
                for (int j = 0; j < 4; ++j) acc[i][j] += av[i] * bv[j];
        }
        __syncthreads();
    }
#pragma unroll
    for (int i = 0; i < 4; ++i)
        *(float4*)&hs[rg * 4 + i][cg * 4] =
            make_float4(acc[i][0] + bi4.x, acc[i][1] + bi4.y,
                        acc[i][2] + bi4.z, acc[i][3] + bi4.w);
    __syncthreads();

    const int r = tid >> 3, kq = tid & 7;
    const int row = row0 + r;
    float hv[16], q[16], kk[16];
    if (row < n) {
#pragma unroll
        for (int i = 0; i < 4; ++i) {
            float4 f = *(const float4*)&hs[r][kq * 16 + i * 4];
            hv[i * 4 + 0] = f.x; hv[i * 4 + 1] = f.y;
            hv[i * 4 + 2] = f.z; hv[i * 4 + 3] = f.w;
        }
        float mu = 0.f;
#pragma unroll
        for (int c = 0; c < 16; ++c) mu += hv[c];
        mu *= (1.f / 16.f);
        float var = 0.f;
#pragma unroll
        for (int c = 0; c < 16; ++c) { float d = hv[c] - mu; var += d * d; }
        var *= (1.f / 16.f);
        float rstd = rsqrtf(var + 1e-6f);
        float qn[16];
#pragma unroll
        for (int c = 0; c < 16; ++c)
            qn[c] = (hv[c] - mu) * rstd * ln_g[c] + ln_b[c];
#pragma unroll
        for (int c = 0; c < 16; ++c) { q[c] = 0.f; kk[c] = 0.f; }
#pragma unroll
        for (int cp = 0; cp < 16; ++cp)
#pragma unroll
            for (int c = 0; c < 16; ++c) {
                q[c]  += qn[cp] * wq[cp * 16 + c];
                kk[c] += hv[cp] * wk[cp * 16 + c];
            }
#pragma unroll
        for (int c = 0; c < 16; ++c) q[c] *= 0.25f;   // 1/sqrt(16)
#pragma unroll
        for (int i = 0; i < 4; ++i)
            *(float4*)&ks[r][kq][i * 4] =
                make_float4(kk[i * 4], kk[i * 4 + 1], kk[i * 4 + 2], kk[i * 4 + 3]);
        float ss = 0.f;
        float rl[16];
#pragma unroll
        for (int c = 0; c < 16; ++c) { rl[c] = fmaxf(hv[c], 0.f); ss += rl[c] * rl[c]; }
        float inv = 1.f / fmaxf(sqrtf(ss), 1e-12f);
        float4* xo = (float4*)(xc0 + (size_t)row * D + kq * DD);
#pragma unroll
        for (int i = 0; i < 4; ++i)
            xo[i] = make_float4(rl[i * 4] * inv, rl[i * 4 + 1] * inv,
                                rl[i * 4 + 2] * inv, rl[i * 4 + 3] * inv);
    }
    __syncthreads();

    float offd = 0.f;
    if (row < n) {
        float s[8];
#pragma unroll
        for (int j = 0; j < 8; ++j) {
            float d = 0.f;
#pragma unroll
            for (int i = 0; i < 4; ++i) {
                float4 f = *(const float4*)&ks[r][j][i * 4];
                d += q[i * 4] * f.x + q[i * 4 + 1] * f.y
                   + q[i * 4 + 2] * f.z + q[i * 4 + 3] * f.w;
            }
            s[j] = d;
        }
        float mx = s[0];
#pragma unroll
        for (int j = 1; j < 8; ++j) mx = fmaxf(mx, s[j]);
        float e[8], se = 0.f;
#pragma unroll
        for (int j = 0; j < 8; ++j) { e[j] = __expf(s[j] - mx); se += e[j]; }
        float rse = 1.f / se;
#pragma unroll
        for (int j = 0; j < 8; ++j)
            if (j != kq) offd += e[j] * rse;
    }
    offd += __shfl_xor(offd, 1);
    offd += __shfl_xor(offd, 2);
    offd += __shfl_xor(offd, 4);
    offd += __shfl_xor(offd, 8);
    offd += __shfl_xor(offd, 16);
    offd += __shfl_xor(offd, 32);
    int lane = tid & 63, wid = tid >> 6;
    if (lane == 0) red[wid] = offd;
    __syncthreads();
    if (tid == 0) partial[blockIdx.x] = red[0] + red[1] + red[2] + red[3];
}

// ---------------------------------------------------------------- partial-sum reduce
__global__ __launch_bounds__(256) void reduce_kernel(
        const float* __restrict__ partial, float* __restrict__ acc, int npart) {
    __shared__ float red[4];
    const int t = threadIdx.x;
    float s = 0.f;
    for (int i = t; i < npart; i += 256) s += partial[i];
    s += __shfl_xor(s, 1);  s += __shfl_xor(s, 2);
    s += __shfl_xor(s, 4);  s += __shfl_xor(s, 8);
    s += __shfl_xor(s, 16); s += __shfl_xor(s, 32);
    if ((t & 63) == 0) red[t >> 6] = s;
    __syncthreads();
    if (t == 0) acc[0] = red[0] + red[1] + red[2] + red[3];
}

// ---------------------------------------------------------------- routing: ONE WAVE PER NODE, f16 z
// R11: z + u_s packed f16 (10-bit mantissa: 8x less error than R10 bf16 —
// absmax margin restored) and the VALU cost halved via HW mixed ops:
// p-step uses v_dot2_f32_f16 (2 MACs/op, f32 accum), u-step multiplies f16
// directly into f32 accumulators (v_fma_mix_f32, no separate cvt).
// Same xor-swizzled uint2 slot layout (2-way bank aliasing = free).
template <bool LAST>
__global__ __launch_bounds__(64) void routing_kernel(
        const float* __restrict__ xc,   // (n+1)*128, normalized, row n = 0
        const int* __restrict__ nb,     // n*32
        float* __restrict__ out,        // LAST ? u1 : xc_next rows [0,n)
        int* __restrict__ amax, int n) {
    __shared__ alignas(16) uint2 zsu[M * 32];       // f16x4 per slot, 8 KB
    __shared__ alignas(8)  uint2 usu[NCAPS * 5];    // u[k] = 4 uint2 (8 f16), stride 5
    __shared__ alignas(16) float pT[NCAPS * 36];    // pT[k][m], f32
    const int l = threadIdx.x;
    const int v = blockIdx.x;
    const int m  = l & 31;
    const int kh = l >> 5;
    const int f4 = m;
    const int mg = kh;

    {
        int sm = l >> 1, sh = l & 1;
        int src = 0;
        if (l < M) {
            int nbv = nb[(size_t)v * M + l];
            src = (nbv < 0) ? n : nbv;
        }
        int srow = __shfl(src, sm);
        const float4* g = (const float4*)(xc + (size_t)srow * D);
#pragma unroll
        for (int i = 0; i < 16; ++i) {
            int f = sh * 16 + i;
            float4 zf = g[f];
            zsu[sm * 32 + (f ^ sm)] =
                make_uint2(pack_h2(zf.x, zf.y), pack_h2(zf.z, zf.w));
        }
    }
    float4 x3 = ((const float4*)(xc + (size_t)v * D))[f4];
    __syncthreads();

    // ---- it 0: p uniform = 1/8 (f16 z -> f32 accum via fma_mix)
    {
        float4 a = make_float4(0.f, 0.f, 0.f, 0.f);
#pragma unroll
        for (int j = 0; j < 16; ++j) {
            int r = mg * 16 + j;
            uint2 zz = zsu[r * 32 + (f4 ^ r)];
            h2 lo = ash2(zz.x), hi = ash2(zz.y);
            a.x += (float)lo.x; a.y += (float)lo.y;
            a.z += (float)hi.x; a.w += (float)hi.y;
        }
        a.x += __shfl_xor(a.x, 32); a.y += __shfl_xor(a.y, 32);
        a.z += __shfl_xor(a.z, 32); a.w += __shfl_xor(a.w, 32);
        a.x = a.x * 0.125f + x3.x;  a.y = a.y * 0.125f + x3.y;
        a.z = a.z * 0.125f + x3.z;  a.w = a.w * 0.125f + x3.w;
        float ss = a.x * a.x + a.y * a.y + a.z * a.z + a.w * a.w;
        ss += __shfl_xor(ss, 1); ss += __shfl_xor(ss, 2);
        float inv = 1.f / fmaxf(sqrtf(ss), 1e-12f);
        if (l < 32)
            usu[(f4 >> 2) * 5 + (f4 & 3)] =
                make_uint2(pack_h2(a.x * inv, a.y * inv),
                           pack_h2(a.z * inv, a.w * inv));
    }
    __syncthreads();

    for (int it = 1; it < ROUTIT; ++it) {
        // ---- p-step: lane (m, kh), k = kh*4+j, dot over 16 ch via fdot2
        float pr[4];
#pragma unroll
        for (int j = 0; j < 4; ++j) {
            float s = 0.f;
            const uint2* uk = &usu[(kh * 4 + j) * 5];
#pragma unroll
            for (int c2 = 0; c2 < 4; ++c2) {
                int f = kh * 16 + j * 4 + c2;
                uint2 zz = zsu[m * 32 + (f ^ m)];
                uint2 uu = uk[c2];
                s = __builtin_amdgcn_fdot2(ash2(zz.x), ash2(uu.x), s, false);
                s = __builtin_amdgcn_fdot2(ash2(zz.y), ash2(uu.y), s, false);
            }
            pr[j] = s;
        }
        float po[4];
#pragma unroll
        for (int j = 0; j < 4; ++j) po[j] = __shfl_xor(pr[j], 32);
        if (LAST && it == ROUTIT - 1) {
            float p8[8];
#pragma unroll
            for (int j = 0; j < 4; ++j) {
                p8[kh * 4 + j] = pr[j];
                p8[(kh ^ 1) * 4 + j] = po[j];
            }
            float bv = p8[0]; int bi = 0;
#pragma unroll
            for (int k2 = 1; k2 < 8; ++k2)
                if (p8[k2] > bv) { bv = p8[k2]; bi = k2; }
            if (l < 32) amax[(size_t)v * M + m] = bi;
        }
        // |p| <= 1 -> max-free softmax
        float er[4], S = 0.f;
#pragma unroll
        for (int j = 0; j < 4; ++j) { er[j] = __expf(pr[j]); S += er[j]; }
#pragma unroll
        for (int j = 0; j < 4; ++j) S += __expf(po[j]);
        float rS = 1.f / S;
#pragma unroll
        for (int j = 0; j < 4; ++j)
            pT[(kh * 4 + j) * 36 + m] = er[j] * rS;
        __syncthreads();

        // ---- u-step: lane (f4, mg) sums 16 rows, f16*f32 fma_mix
        float pk[16];
        {
            const int k2 = f4 >> 2;
#pragma unroll
            for (int j4 = 0; j4 < 4; ++j4) {
                float4 pp = *(const float4*)&pT[k2 * 36 + mg * 16 + j4 * 4];
                pk[j4 * 4 + 0] = pp.x; pk[j4 * 4 + 1] = pp.y;
                pk[j4 * 4 + 2] = pp.z; pk[j4 * 4 + 3] = pp.w;
            }
        }
        float4 a = make_float4(0.f, 0.f, 0.f, 0.f);
#pragma unroll
        for (int j = 0; j < 16; ++j) {
            int r = mg * 16 + j;
            uint2 zz = zsu[r * 32 + (f4 ^ r)];
            h2 lo = ash2(zz.x), hi = ash2(zz.y);
            a.x += (float)lo.x * pk[j]; a.y += (float)lo.y * pk[j];
            a.z += (float)hi.x * pk[j]; a.w += (float)hi.y * pk[j];
        }
        a.x += __shfl_xor(a.x, 32); a.y += __shfl_xor(a.y, 32);
        a.z += __shfl_xor(a.z, 32); a.w += __shfl_xor(a.w, 32);
        a.x += x3.x; a.y += x3.y; a.z += x3.z; a.w += x3.w;

        if (it < ROUTIT - 1) {
            float ss = a.x * a.x + a.y * a.y + a.z * a.z + a.w * a.w;
            ss += __shfl_xor(ss, 1); ss += __shfl_xor(ss, 2);
            float inv = 1.f / fmaxf(sqrtf(ss), 1e-12f);
            if (l < 32)
                usu[(f4 >> 2) * 5 + (f4 & 3)] =
                    make_uint2(pack_h2(a.x * inv, a.y * inv),
                               pack_h2(a.z * inv, a.w * inv));
            __syncthreads();
        } else if (LAST) {
            if (l < 32) ((float4*)(out + (size_t)v * D))[f4] = a;
        } else {
            float r0 = fmaxf(a.x, 0.f), r1 = fmaxf(a.y, 0.f);
            float r2 = fmaxf(a.z, 0.f), r3 = fmaxf(a.w, 0.f);
            float ss = r0 * r0 + r1 * r1 + r2 * r2 + r3 * r3;
            ss += __shfl_xor(ss, 1); ss += __shfl_xor(ss, 2);
            float inv = 1.f / fmaxf(sqrtf(ss), 1e-12f);
            if (l < 32)
                ((float4*)(out + (size_t)v * D))[f4] =
                    make_float4(r0 * inv, r1 * inv, r2 * inv, r3 * inv);
        }
    }
}

// ---------------------------------------------------------------- second-hop presum
__global__ __launch_bounds__(256) void s2_kernel(
        const float* __restrict__ xc1, const int* __restrict__ nb,
        const int* __restrict__ amax, float* __restrict__ s2, int n) {
    int idx = blockIdx.x * 256 + threadIdx.x;
    if (idx >= n * 16) return;
    int w = idx >> 4, c = idx & 15;
    float s = 0.f;
#pragma unroll
    for (int b = 0; b < CUT; ++b) {
        int t  = nb[(size_t)w * M + b];
        int jj = amax[(size_t)w * M + b];
        int im = (t < 0) ? n : t;   // row n = zeros
        s += xc1[(size_t)im * D + jj * DD + c];
    }
    s2[idx] = s;
}

// ---------------------------------------------------------------- meta gather + MLP + log_softmax
__global__ __launch_bounds__(256) void meta_kernel(
        const float* __restrict__ u1, const float* __restrict__ s2,
        const int* __restrict__ nb, const int* __restrict__ amax,
        const float* __restrict__ mlp_w, const float* __restrict__ mlp_b,
        const float* __restrict__ attn_acc, float* __restrict__ d_out, int n) {
    __shared__ float Wl[128 * 16];
    __shared__ float accs[16][132];
    const int t = threadIdx.x;
#pragma unroll
    for (int i = 0; i < 8; ++i) Wl[t + i * 256] = mlp_w[t + i * 256];
    const int g = t >> 4, c = t & 15;
    const int v = blockIdx.x * 16 + g;
    if (blockIdx.x == 0 && t == 0)
        d_out[(size_t)n * 16] = attn_acc[0] * (1.f / (56.f * (float)n));
    if (v < n) {
#pragma unroll
        for (int i = 0; i < 8; ++i) accs[g][i * 16 + c] = 0.f;
        for (int a = 0; a < CUT; ++a) {
            int w = nb[(size_t)v * M + a];
            if (w < 0) continue;
            int i = amax[(size_t)v * M + a];   // first-hop capsule
            accs[g][i * 16 + c] += s2[(size_t)w * 16 + c];
        }
#pragma unroll
        for (int i = 0; i < 8; ++i) {
            float meta = u1[(size_t)v * D + i * 16 + c] + accs[g][i * 16 + c] * (1.f / 25.f);
            accs[g][i * 16 + c] = fmaxf(meta, 0.f);
        }
    }
    __syncthreads();
    if (v < n) {
        float o = mlp_b[c];
#pragma unroll
        for (int dd = 0; dd < 128; ++dd) o += accs[g][dd] * Wl[dd * 16 + c];
        float mx = o;
        mx = fmaxf(mx, __shfl_xor(mx, 1));
        mx = fmaxf(mx, __shfl_xor(mx, 2));
        mx = fmaxf(mx, __shfl_xor(mx, 4));
        mx = fmaxf(mx, __shfl_xor(mx, 8));
        float e = __expf(o - mx);
        float se = wred16_sum(e);
        float ls = (o - mx) - logf(se);
        d_out[(size_t)v * 16 + c] = ls;
        d_out[(size_t)n * 16 + 1 + (size_t)v * 16 + c] = o;
    }
}

// ---------------------------------------------------------------- launch
extern "C" void kernel_launch(void* const* d_in, const int* in_sizes, int n_in,
                              void* d_out, int out_size, void* d_ws, size_t ws_size,
                              hipStream_t stream) {
    const float* x     = (const float*)d_in[0];
    const int*   nb    = (const int*)d_in[1];
    const float* pca_w = (const float*)d_in[2];
    const float* pca_b = (const float*)d_in[3];
    const float* ln_g  = (const float*)d_in[4];
    const float* ln_b  = (const float*)d_in[5];
    const float* w_qs  = (const float*)d_in[6];
    const float* w_ks  = (const float*)d_in[7];
    const float* mlp_w = (const float*)d_in[8];
    const float* mlp_b = (const float*)d_in[9];
    float* out = (float*)d_out;

    const int d = 128;
    const int nfeat = in_sizes[2] / d;      // 500
    const int n = in_sizes[0] / nfeat;      // 20000
    const int nblk = (n + 31) / 32;         // fused pca_attn blocks (625)

    float* bufA = (float*)d_ws;                       // n*128 : u1
    float* bufB = bufA + (size_t)n * d;               // (n+1)*128 : xc0; later amax+s2
    float* bufC = bufB + (size_t)(n + 1) * d;         // (n+1)*128 : xc1
    float* acc  = bufC + (size_t)(n + 1) * d;         // 1 float : attn loss sum
    int* amax = (int*)bufB;                           // n*32 ints (xc0 dead)
    float* s2 = bufB + (size_t)n * M;                 // n*16 floats, after amax
    float* partial = bufC;                            // overlay, consumed pre-routing

    init_kernel<<<1, 256, 0, stream>>>(bufB, bufC, n);
    pca_attn<<<nblk, 256, 0, stream>>>(x, pca_w, pca_b, ln_g, ln_b, w_qs, w_ks,
                                       bufB, partial, n, nfeat);
    reduce_kernel<<<1, 256, 0, stream>>>(partial, acc, nblk);
    routing_kernel<false><<<n, 64, 0, stream>>>(bufB, nb, bufC, nullptr, n);
    routing_kernel<true><<<n, 64, 0, stream>>>(bufC, nb, bufA, amax, n);
    s2_kernel<<<(n * 16 + 255) / 256, 256, 0, stream>>>(bufC, nb, amax, s2, n);
    meta_kernel<<<(n + 15) / 16, 256, 0, stream>>>(bufA, s2, nb, amax, mlp_w, mlp_b, acc, out, n);
}

// Round 12
// 275.163 us; speedup vs baseline: 1.4247x; 1.0417x over previous
//
#include <hip/hip_runtime.h>
#include <math.h>

#define NCAPS 8
#define DD    16
#define D     128
#define M     32
#define ROUTIT 6
#define CUT   5

__device__ __forceinline__ float wred16_sum(float v) {
    v += __shfl_xor(v, 1);
    v += __shfl_xor(v, 2);
    v += __shfl_xor(v, 4);
    v += __shfl_xor(v, 8);
    return v;
}

// ---- f16 pair pack/unpack (RNE via default float->_Float16 conversion)
typedef _Float16 h2 __attribute__((ext_vector_type(2)));
union U32H2 { unsigned u; h2 h; };
__device__ __forceinline__ unsigned pack_h2(float a, float b) {
    U32H2 r; r.h.x = (_Float16)a; r.h.y = (_Float16)b; return r.u;
}
__device__ __forceinline__ h2 ash2(unsigned u) { U32H2 r; r.u = u; return r.h; }

// ---------------------------------------------------------------- init
__global__ void init_kernel(float* xc0, float* xc1, int n) {
    int t = threadIdx.x;
    if (t < D) {
        xc0[(size_t)n * D + t] = 0.f;   // dummy row n = 0
        xc1[(size_t)n * D + t] = 0.f;
    }
}

// ---------------------------------------------------------------- fused PCA GEMM + attn loss + xc0
// R12: phase-1 GEMM in f16 pairs via v_dot2_f32_f16 (halves DS insts AND
// VALU), register-prefetch pipeline (hides global staging latency), ks
// aliased over the staging buffers (LDS 52.7 -> ~39.4 KB, 4 blocks/CU).
__global__ __launch_bounds__(256) void pca_attn(
        const float* __restrict__ x, const float* __restrict__ w,
        const float* __restrict__ bias, const float* __restrict__ ln_g,
        const float* __restrict__ ln_b, const float* __restrict__ w_qs,
        const float* __restrict__ w_ks, float* __restrict__ xc0,
        float* __restrict__ partial, int n, int nfeat) {
    // union region: phase1 staging (xs2+ws2 = 6.6 KB) / phase3 ks (20.5 KB)
    __shared__ alignas(16) unsigned char uS[20480];
    unsigned (*xs2)[36]  = (unsigned(*)[36])uS;            // [kkp][row]
    unsigned (*ws2)[128] = (unsigned(*)[128])(uS + 1440);  // [kkp][col]
    float (*ks)[8][20]   = (float(*)[8][20])uS;            // [row][kq][c]
    __shared__ alignas(16) float hs[32][132];              // h tile, +4 pad
    __shared__ float wq[256], wk[256];
    __shared__ float red[4];
    const int tid = threadIdx.x;
    const int cg = tid & 31;
    const int rg = tid >> 5;
    const int row0 = blockIdx.x * 32;
    wq[tid] = w_qs[tid];
    wk[tid] = w_ks[tid];
    const float4 bi4 = *(const float4*)&bias[cg * 4];

    // ---- phase 1: f16-pair GEMM, 25 tiles of BK=20 (10 kk-pairs)
    const int xr_r = tid / 5, xr_cf = tid % 5;          // x-loader role (tid<160)
    const int wk0 = tid >> 5, wc0 = tid & 31;           // w task 0 (kkp 0..7)
    float4 xr{}, w0a{}, w0b{}, w1a{}, w1b{};

    // preload tile 0
    {
        if (tid < 160) {
            int row = row0 + xr_r;
            xr = (row < n) ? *(const float4*)&x[(size_t)row * nfeat + xr_cf * 4]
                           : make_float4(0.f, 0.f, 0.f, 0.f);
        }
        w0a = *(const float4*)&w[(size_t)(2 * wk0) * 128 + wc0 * 4];
        w0b = *(const float4*)&w[(size_t)(2 * wk0 + 1) * 128 + wc0 * 4];
        if (tid < 64) {
            int kkp = 8 + (tid >> 5);
            w1a = *(const float4*)&w[(size_t)(2 * kkp) * 128 + wc0 * 4];
            w1b = *(const float4*)&w[(size_t)(2 * kkp + 1) * 128 + wc0 * 4];
        }
    }
    float acc[4][4] = {};
    const int ntile = nfeat / 20;   // 25
    for (int t = 0; t < ntile; ++t) {
        __syncthreads();   // previous tile's readers done
        // store prefetched regs -> LDS (f16 pairs)
        if (tid < 160) {
            xs2[xr_cf * 2 + 0][xr_r] = pack_h2(xr.x, xr.y);
            xs2[xr_cf * 2 + 1][xr_r] = pack_h2(xr.z, xr.w);
        }
        {
            uint4 pw;
            pw.x = pack_h2(w0a.x, w0b.x); pw.y = pack_h2(w0a.y, w0b.y);
            pw.z = pack_h2(w0a.z, w0b.z); pw.w = pack_h2(w0a.w, w0b.w);
            *(uint4*)&ws2[wk0][wc0 * 4] = pw;
        }
        if (tid < 64) {
            int kkp = 8 + (tid >> 5);
            uint4 pw;
            pw.x = pack_h2(w1a.x, w1b.x); pw.y = pack_h2(w1a.y, w1b.y);
            pw.z = pack_h2(w1a.z, w1b.z); pw.w = pack_h2(w1a.w, w1b.w);
            *(uint4*)&ws2[kkp][wc0 * 4] = pw;
        }
        // issue next tile's loads (in flight during compute)
        if (t < ntile - 1) {
            int k0 = (t + 1) * 20;
            if (tid < 160) {
                int row = row0 + xr_r;
                xr = (row < n)
                    ? *(const float4*)&x[(size_t)row * nfeat + k0 + xr_cf * 4]
                    : make_float4(0.f, 0.f, 0.f, 0.f);
            }
            w0a = *(const float4*)&w[(size_t)(k0 + 2 * wk0) * 128 + wc0 * 4];
            w0b = *(const float4*)&w[(size_t)(k0 + 2 * wk0 + 1) * 128 + wc0 * 4];
            if (tid < 64) {
                int kkp = 8 + (tid >> 5);
                w1a = *(const float4*)&w[(size_t)(k0 + 2 * kkp) * 128 + wc0 * 4];
                w1b = *(const float4*)&w[(size_t)(k0 + 2 * kkp + 1) * 128 + wc0 * 4];
            }
        }
        __syncthreads();   // LDS tile ready
#pragma unroll
        for (int kkp = 0; kkp < 10; ++kkp) {
            uint4 av = *(const uint4*)&xs2[kkp][rg * 4];   // 4 rows (broadcast)
            uint4 bv = *(const uint4*)&ws2[kkp][cg * 4];   // 4 cols
            unsigned aa[4] = {av.x, av.y, av.z, av.w};
            unsigned bb[4] = {bv.x, bv.y, bv.z, bv.w};
#pragma unroll
            for (int i = 0; i < 4; ++i)
#pragma unroll
                for (int j = 0; j < 4; ++j)
                    acc[i][j] = __builtin_amdgcn_fdot2(ash2(aa[i]), ash2(bb[j]),
                                                       acc[i][j], false);
        }
    }
#pragma unroll
    for (int i = 0; i < 4; ++i)
        *(float4*)&hs[rg * 4 + i][cg * 4] =
            make_float4(acc[i][0] + bi4.x, acc[i][1] + bi4.y,
                        acc[i][2] + bi4.z, acc[i][3] + bi4.w);
    __syncthreads();   // hs ready; staging buffers dead -> ks may reuse

    // ---- phase 2: per-(row, capsule) LN + q/kk matmuls + xc0
    const int r = tid >> 3, kq = tid & 7;
    const int row = row0 + r;
    float hv[16], q[16], kk[16];
    if (row < n) {
#pragma unroll
        for (int i = 0; i < 4; ++i) {
            float4 f = *(const float4*)&hs[r][kq * 16 + i * 4];
            hv[i * 4 + 0] = f.x; hv[i * 4 + 1] = f.y;
            hv[i * 4 + 2] = f.z; hv[i * 4 + 3] = f.w;
        }
        float mu = 0.f;
#pragma unroll
        for (int c = 0; c < 16; ++c) mu += hv[c];
        mu *= (1.f / 16.f);
        float var = 0.f;
#pragma unroll
        for (int c = 0; c < 16; ++c) { float d = hv[c] - mu; var += d * d; }
        var *= (1.f / 16.f);
        float rstd = rsqrtf(var + 1e-6f);
        float qn[16];
#pragma unroll
        for (int c = 0; c < 16; ++c)
            qn[c] = (hv[c] - mu) * rstd * ln_g[c] + ln_b[c];
#pragma unroll
        for (int c = 0; c < 16; ++c) { q[c] = 0.f; kk[c] = 0.f; }
#pragma unroll
        for (int cp = 0; cp < 16; ++cp)
#pragma unroll
            for (int c = 0; c < 16; ++c) {
                q[c]  += qn[cp] * wq[cp * 16 + c];
                kk[c] += hv[cp] * wk[cp * 16 + c];
            }
#pragma unroll
        for (int c = 0; c < 16; ++c) q[c] *= 0.25f;   // 1/sqrt(16)
#pragma unroll
        for (int i = 0; i < 4; ++i)
            *(float4*)&ks[r][kq][i * 4] =
                make_float4(kk[i * 4], kk[i * 4 + 1], kk[i * 4 + 2], kk[i * 4 + 3]);
        float ss = 0.f;
        float rl[16];
#pragma unroll
        for (int c = 0; c < 16; ++c) { rl[c] = fmaxf(hv[c], 0.f); ss += rl[c] * rl[c]; }
        float inv = 1.f / fmaxf(sqrtf(ss), 1e-12f);
        float4* xo = (float4*)(xc0 + (size_t)row * D + kq * DD);
#pragma unroll
        for (int i = 0; i < 4; ++i)
            xo[i] = make_float4(rl[i * 4] * inv, rl[i * 4 + 1] * inv,
                                rl[i * 4 + 2] * inv, rl[i * 4 + 3] * inv);
    }
    __syncthreads();

    // ---- phase 3: scores row kq vs all 8 keys; softmax; off-diag sum
    float offd = 0.f;
    if (row < n) {
        float s[8];
#pragma unroll
        for (int j = 0; j < 8; ++j) {
            float d = 0.f;
#pragma unroll
            for (int i = 0; i < 4; ++i) {
                float4 f = *(const float4*)&ks[r][j][i * 4];
                d += q[i * 4] * f.x + q[i * 4 + 1] * f.y
                   + q[i * 4 + 2] * f.z + q[i * 4 + 3] * f.w;
            }
            s[j] = d;
        }
        float mx = s[0];
#pragma unroll
        for (int j = 1; j < 8; ++j) mx = fmaxf(mx, s[j]);
        float e[8], se = 0.f;
#pragma unroll
        for (int j = 0; j < 8; ++j) { e[j] = __expf(s[j] - mx); se += e[j]; }
        float rse = 1.f / se;
#pragma unroll
        for (int j = 0; j < 8; ++j)
            if (j != kq) offd += e[j] * rse;
    }
    offd += __shfl_xor(offd, 1);
    offd += __shfl_xor(offd, 2);
    offd += __shfl_xor(offd, 4);
    offd += __shfl_xor(offd, 8);
    offd += __shfl_xor(offd, 16);
    offd += __shfl_xor(offd, 32);
    int lane = tid & 63, wid = tid >> 6;
    if (lane == 0) red[wid] = offd;
    __syncthreads();
    if (tid == 0) partial[blockIdx.x] = red[0] + red[1] + red[2] + red[3];
}

// ---------------------------------------------------------------- partial-sum reduce
__global__ __launch_bounds__(256) void reduce_kernel(
        const float* __restrict__ partial, float* __restrict__ acc, int npart) {
    __shared__ float red[4];
    const int t = threadIdx.x;
    float s = 0.f;
    for (int i = t; i < npart; i += 256) s += partial[i];
    s += __shfl_xor(s, 1);  s += __shfl_xor(s, 2);
    s += __shfl_xor(s, 4);  s += __shfl_xor(s, 8);
    s += __shfl_xor(s, 16); s += __shfl_xor(s, 32);
    if ((t & 63) == 0) red[t >> 6] = s;
    __syncthreads();
    if (t == 0) acc[0] = red[0] + red[1] + red[2] + red[3];
}

// ---------------------------------------------------------------- routing: ONE WAVE PER NODE, f16 z
// (unchanged from R11)
template <bool LAST>
__global__ __launch_bounds__(64) void routing_kernel(
        const float* __restrict__ xc,   // (n+1)*128, normalized, row n = 0
        const int* __restrict__ nb,     // n*32
        float* __restrict__ out,        // LAST ? u1 : xc_next rows [0,n)
        int* __restrict__ amax, int n) {
    __shared__ alignas(16) uint2 zsu[M * 32];       // f16x4 per slot, 8 KB
    __shared__ alignas(8)  uint2 usu[NCAPS * 5];    // u[k] = 4 uint2, stride 5
    __shared__ alignas(16) float pT[NCAPS * 36];    // pT[k][m], f32
    const int l = threadIdx.x;
    const int v = blockIdx.x;
    const int m  = l & 31;
    const int kh = l >> 5;
    const int f4 = m;
    const int mg = kh;

    {
        int sm = l >> 1, sh = l & 1;
        int src = 0;
        if (l < M) {
            int nbv = nb[(size_t)v * M + l];
            src = (nbv < 0) ? n : nbv;
        }
        int srow = __shfl(src, sm);
        const float4* g = (const float4*)(xc + (size_t)srow * D);
#pragma unroll
        for (int i = 0; i < 16; ++i) {
            int f = sh * 16 + i;
            float4 zf = g[f];
            zsu[sm * 32 + (f ^ sm)] =
                make_uint2(pack_h2(zf.x, zf.y), pack_h2(zf.z, zf.w));
        }
    }
    float4 x3 = ((const float4*)(xc + (size_t)v * D))[f4];
    __syncthreads();

    {
        float4 a = make_float4(0.f, 0.f, 0.f, 0.f);
#pragma unroll
        for (int j = 0; j < 16; ++j) {
            int r = mg * 16 + j;
            uint2 zz = zsu[r * 32 + (f4 ^ r)];
            h2 lo = ash2(zz.x), hi = ash2(zz.y);
            a.x += (float)lo.x; a.y += (float)lo.y;
            a.z += (float)hi.x; a.w += (float)hi.y;
        }
        a.x += __shfl_xor(a.x, 32); a.y += __shfl_xor(a.y, 32);
        a.z += __shfl_xor(a.z, 32); a.w += __shfl_xor(a.w, 32);
        a.x = a.x * 0.125f + x3.x;  a.y = a.y * 0.125f + x3.y;
        a.z = a.z * 0.125f + x3.z;  a.w = a.w * 0.125f + x3.w;
        float ss = a.x * a.x + a.y * a.y + a.z * a.z + a.w * a.w;
        ss += __shfl_xor(ss, 1); ss += __shfl_xor(ss, 2);
        float inv = 1.f / fmaxf(sqrtf(ss), 1e-12f);
        if (l < 32)
            usu[(f4 >> 2) * 5 + (f4 & 3)] =
                make_uint2(pack_h2(a.x * inv, a.y * inv),
                           pack_h2(a.z * inv, a.w * inv));
    }
    __syncthreads();

    for (int it = 1; it < ROUTIT; ++it) {
        float pr[4];
#pragma unroll
        for (int j = 0; j < 4; ++j) {
            float s = 0.f;
            const uint2* uk = &usu[(kh * 4 + j) * 5];
#pragma unroll
            for (int c2 = 0; c2 < 4; ++c2) {
                int f = kh * 16 + j * 4 + c2;
                uint2 zz = zsu[m * 32 + (f ^ m)];
                uint2 uu = uk[c2];
                s = __builtin_amdgcn_fdot2(ash2(zz.x), ash2(uu.x), s, false);
                s = __builtin_amdgcn_fdot2(ash2(zz.y), ash2(uu.y), s, false);
            }
            pr[j] = s;
        }
        float po[4];
#pragma unroll
        for (int j = 0; j < 4; ++j) po[j] = __shfl_xor(pr[j], 32);
        if (LAST && it == ROUTIT - 1) {
            float p8[8];
#pragma unroll
            for (int j = 0; j < 4; ++j) {
                p8[kh * 4 + j] = pr[j];
                p8[(kh ^ 1) * 4 + j] = po[j];
            }
            float bv = p8[0]; int bi = 0;
#pragma unroll
            for (int k2 = 1; k2 < 8; ++k2)
                if (p8[k2] > bv) { bv = p8[k2]; bi = k2; }
            if (l < 32) amax[(size_t)v * M + m] = bi;
        }
        float er[4], S = 0.f;
#pragma unroll
        for (int j = 0; j < 4; ++j) { er[j] = __expf(pr[j]); S += er[j]; }
#pragma unroll
        for (int j = 0; j < 4; ++j) S += __expf(po[j]);
        float rS = 1.f / S;
#pragma unroll
        for (int j = 0; j < 4; ++j)
            pT[(kh * 4 + j) * 36 + m] = er[j] * rS;
        __syncthreads();

        float pk[16];
        {
            const int k2 = f4 >> 2;
#pragma unroll
            for (int j4 = 0; j4 < 4; ++j4) {
                float4 pp = *(const float4*)&pT[k2 * 36 + mg * 16 + j4 * 4];
                pk[j4 * 4 + 0] = pp.x; pk[j4 * 4 + 1] = pp.y;
                pk[j4 * 4 + 2] = pp.z; pk[j4 * 4 + 3] = pp.w;
            }
        }
        float4 a = make_float4(0.f, 0.f, 0.f, 0.f);
#pragma unroll
        for (int j = 0; j < 16; ++j) {
            int r = mg * 16 + j;
            uint2 zz = zsu[r * 32 + (f4 ^ r)];
            h2 lo = ash2(zz.x), hi = ash2(zz.y);
            a.x += (float)lo.x * pk[j]; a.y += (float)lo.y * pk[j];
            a.z += (float)hi.x * pk[j]; a.w += (float)hi.y * pk[j];
        }
        a.x += __shfl_xor(a.x, 32); a.y += __shfl_xor(a.y, 32);
        a.z += __shfl_xor(a.z, 32); a.w += __shfl_xor(a.w, 32);
        a.x += x3.x; a.y += x3.y; a.z += x3.z; a.w += x3.w;

        if (it < ROUTIT - 1) {
            float ss = a.x * a.x + a.y * a.y + a.z * a.z + a.w * a.w;
            ss += __shfl_xor(ss, 1); ss += __shfl_xor(ss, 2);
            float inv = 1.f / fmaxf(sqrtf(ss), 1e-12f);
            if (l < 32)
                usu[(f4 >> 2) * 5 + (f4 & 3)] =
                    make_uint2(pack_h2(a.x * inv, a.y * inv),
                               pack_h2(a.z * inv, a.w * inv));
            __syncthreads();
        } else if (LAST) {
            if (l < 32) ((float4*)(out + (size_t)v * D))[f4] = a;
        } else {
            float r0 = fmaxf(a.x, 0.f), r1 = fmaxf(a.y, 0.f);
            float r2 = fmaxf(a.z, 0.f), r3 = fmaxf(a.w, 0.f);
            float ss = r0 * r0 + r1 * r1 + r2 * r2 + r3 * r3;
            ss += __shfl_xor(ss, 1); ss += __shfl_xor(ss, 2);
            float inv = 1.f / fmaxf(sqrtf(ss), 1e-12f);
            if (l < 32)
                ((float4*)(out + (size_t)v * D))[f4] =
                    make_float4(r0 * inv, r1 * inv, r2 * inv, r3 * inv);
        }
    }
}

// ---------------------------------------------------------------- second-hop presum
__global__ __launch_bounds__(256) void s2_kernel(
        const float* __restrict__ xc1, const int* __restrict__ nb,
        const int* __restrict__ amax, float* __restrict__ s2, int n) {
    int idx = blockIdx.x * 256 + threadIdx.x;
    if (idx >= n * 16) return;
    int w = idx >> 4, c = idx & 15;
    float s = 0.f;
#pragma unroll
    for (int b = 0; b < CUT; ++b) {
        int t  = nb[(size_t)w * M + b];
        int jj = amax[(size_t)w * M + b];
        int im = (t < 0) ? n : t;   // row n = zeros
        s += xc1[(size_t)im * D + jj * DD + c];
    }
    s2[idx] = s;
}

// ---------------------------------------------------------------- meta gather + MLP + log_softmax
__global__ __launch_bounds__(256) void meta_kernel(
        const float* __restrict__ u1, const float* __restrict__ s2,
        const int* __restrict__ nb, const int* __restrict__ amax,
        const float* __restrict__ mlp_w, const float* __restrict__ mlp_b,
        const float* __restrict__ attn_acc, float* __restrict__ d_out, int n) {
    __shared__ float Wl[128 * 16];
    __shared__ float accs[16][132];
    const int t = threadIdx.x;
#pragma unroll
    for (int i = 0; i < 8; ++i) Wl[t + i * 256] = mlp_w[t + i * 256];
    const int g = t >> 4, c = t & 15;
    const int v = blockIdx.x * 16 + g;
    if (blockIdx.x == 0 && t == 0)
        d_out[(size_t)n * 16] = attn_acc[0] * (1.f / (56.f * (float)n));
    if (v < n) {
#pragma unroll
        for (int i = 0; i < 8; ++i) accs[g][i * 16 + c] = 0.f;
        for (int a = 0; a < CUT; ++a) {
            int w = nb[(size_t)v * M + a];
            if (w < 0) continue;
            int i = amax[(size_t)v * M + a];   // first-hop capsule
            accs[g][i * 16 + c] += s2[(size_t)w * 16 + c];
        }
#pragma unroll
        for (int i = 0; i < 8; ++i) {
            float meta = u1[(size_t)v * D + i * 16 + c] + accs[g][i * 16 + c] * (1.f / 25.f);
            accs[g][i * 16 + c] = fmaxf(meta, 0.f);
        }
    }
    __syncthreads();
    if (v < n) {
        float o = mlp_b[c];
#pragma unroll
        for (int dd = 0; dd < 128; ++dd) o += accs[g][dd] * Wl[dd * 16 + c];
        float mx = o;
        mx = fmaxf(mx, __shfl_xor(mx, 1));
        mx = fmaxf(mx, __shfl_xor(mx, 2));
        mx = fmaxf(mx, __shfl_xor(mx, 4));
        mx = fmaxf(mx, __shfl_xor(mx, 8));
        float e = __expf(o - mx);
        float se = wred16_sum(e);
        float ls = (o - mx) - logf(se);
        d_out[(size_t)v * 16 + c] = ls;
        d_out[(size_t)n * 16 + 1 + (size_t)v * 16 + c] = o;
    }
}

// ---------------------------------------------------------------- launch
extern "C" void kernel_launch(void* const* d_in, const int* in_sizes, int n_in,
                              void* d_out, int out_size, void* d_ws, size_t ws_size,
                              hipStream_t stream) {
    const float* x     = (const float*)d_in[0];
    const int*   nb    = (const int*)d_in[1];
    const float* pca_w = (const float*)d_in[2];
    const float* pca_b = (const float*)d_in[3];
    const float* ln_g  = (const float*)d_in[4];
    const float* ln_b  = (const float*)d_in[5];
    const float* w_qs  = (const float*)d_in[6];
    const float* w_ks  = (const float*)d_in[7];
    const float* mlp_w = (const float*)d_in[8];
    const float* mlp_b = (const float*)d_in[9];
    float* out = (float*)d_out;

    const int d = 128;
    const int nfeat = in_sizes[2] / d;      // 500
    const int n = in_sizes[0] / nfeat;      // 20000
    const int nblk = (n + 31) / 32;         // fused pca_attn blocks (625)

    float* bufA = (float*)d_ws;                       // n*128 : u1
    float* bufB = bufA + (size_t)n * d;               // (n+1)*128 : xc0; later amax+s2
    float* bufC = bufB + (size_t)(n + 1) * d;         // (n+1)*128 : xc1
    float* acc  = bufC + (size_t)(n + 1) * d;         // 1 float : attn loss sum
    int* amax = (int*)bufB;                           // n*32 ints (xc0 dead)
    float* s2 = bufB + (size_t)n * M;                 // n*16 floats, after amax
    float* partial = bufC;                            // overlay, consumed pre-routing

    init_kernel<<<1, 256, 0, stream>>>(bufB, bufC, n);
    pca_attn<<<nblk, 256, 0, stream>>>(x, pca_w, pca_b, ln_g, ln_b, w_qs, w_ks,
                                       bufB, partial, n, nfeat);
    reduce_kernel<<<1, 256, 0, stream>>>(partial, acc, nblk);
    routing_kernel<false><<<n, 64, 0, stream>>>(bufB, nb, bufC, nullptr, n);
    routing_kernel<true><<<n, 64, 0, stream>>>(bufC, nb, bufA, amax, n);
    s2_kernel<<<(n * 16 + 255) / 256, 256, 0, stream>>>(bufC, nb, amax, s2, n);
    meta_kernel<<<(n + 15) / 16, 256, 0, stream>>>(bufA, s2, nb, amax, mlp_w, mlp_b, acc, out, n);
}